// Round 1
// baseline (549.631 us; speedup 1.0000x reference)
//
#include <hip/hip_runtime.h>

typedef unsigned short us;
typedef us s8v __attribute__((ext_vector_type(8)));   // 8 bf16 (4 VGPRs)
typedef us s4v __attribute__((ext_vector_type(4)));
typedef float f4v __attribute__((ext_vector_type(4)));

static __device__ __forceinline__ us f2b(float f) {
  unsigned u = __builtin_bit_cast(unsigned, f);
  return (us)((u + 0x7fffu + ((u >> 16) & 1u)) >> 16);   // RNE fp32->bf16
}
static __device__ __forceinline__ float b2f(us s) {
  unsigned u = ((unsigned)s) << 16;
  return __builtin_bit_cast(float, u);
}

// ---------------- flat f32 -> bf16 cast ----------------
__global__ __launch_bounds__(256) void castk(const float* __restrict__ in,
                                             us* __restrict__ out, int n4) {
  int i = blockIdx.x * 256 + threadIdx.x;
  int stride = gridDim.x * 256;
  for (; i < n4; i += stride) {
    float4 v = ((const float4*)in)[i];
    s4v s = {f2b(v.x), f2b(v.y), f2b(v.z), f2b(v.w)};
    ((s4v*)out)[i] = s;
  }
}

// ---------------- transpose-cast: f32 [R][C] -> bf16 [C][R] ----------------
__global__ __launch_bounds__(256) void tcast(const float* __restrict__ in,
                                             us* __restrict__ out, int R, int C) {
  __shared__ float t[64][65];
  const int tid = threadIdx.x;
  const long r0 = (long)blockIdx.y * 64, c0 = (long)blockIdx.x * 64;
#pragma unroll
  for (int j = 0; j < 4; ++j) {
    int idx = j * 256 + tid;
    int row = idx >> 4, c4 = (idx & 15) * 4;
    float4 v = *(const float4*)(in + (r0 + row) * C + c0 + c4);
    t[row][c4] = v.x; t[row][c4 + 1] = v.y; t[row][c4 + 2] = v.z; t[row][c4 + 3] = v.w;
  }
  __syncthreads();
#pragma unroll
  for (int j = 0; j < 4; ++j) {
    int idx = j * 256 + tid;
    int orow = idx >> 4, r4 = (idx & 15) * 4;
    s4v s = {f2b(t[r4][orow]), f2b(t[r4 + 1][orow]), f2b(t[r4 + 2][orow]), f2b(t[r4 + 3][orow])};
    *(s4v*)(out + (c0 + orow) * R + r0 + r4) = s;
  }
}

// byte-offset into a [128 rows][128 B] LDS tile, XOR-swizzled (T2)
#define SW(row, kb) ((row) * 128 + ((kb) ^ (((row) & 7) << 4)))

// ---------------- generic NT bf16 MFMA GEMM, 128x128 tile, BK=64 ----------------
// C[row][col] = sum_k A[row][k] * B[col][k]  (+ epilogue)
// EPI 0: out_b16[row*2048+col] = v + b2f(addb16[same]) + bias[row]        (MLP -> xf_t)
// EPI 1: out_b16[((z*2+(col>>7))*4096+row)*128+(col&127)] = v + bias[col] (theta/phi -> [bh][n][d])
// EPI 2: out_b16[(z*256+row)*4096+col] = v + bias[row]                    (g -> [b][IC][n])
// EPI 3: outf32[(z*512+row)*4096+col] = v + bias[row] + addf32[same]      (final output)
template <int EPI, int AF32, int BF32>
__global__ __launch_bounds__(256) void gemm_nt(
    const void* __restrict__ Av, const void* __restrict__ Bv,
    int lda, int ldb, int K, long aZ, long bZ,
    const float* __restrict__ bias,
    const us* __restrict__ addb16,
    const float* __restrict__ addf32,
    us* __restrict__ outb16,
    float* __restrict__ outf32) {
  __shared__ __align__(16) us lA[128 * 64];
  __shared__ __align__(16) us lB[128 * 64];
  const int tid = threadIdx.x, l = tid & 63;
  const int lr = l & 15, lg = l >> 4;
  const int w = tid >> 6, wr = w >> 1, wc = w & 1;
  const int bm = blockIdx.x, bn = blockIdx.y, z = blockIdx.z;
  const f4v zero = {0.f, 0.f, 0.f, 0.f};
  f4v acc[4][4];
#pragma unroll
  for (int i = 0; i < 4; ++i)
#pragma unroll
    for (int j = 0; j < 4; ++j) acc[i][j] = zero;
  char* lab = (char*)lA;
  char* lbb = (char*)lB;

  for (int k0 = 0; k0 < K; k0 += 64) {
#pragma unroll
    for (int j = 0; j < 4; ++j) {
      int byte = j * 4096 + tid * 16;
      int row = byte >> 7, kb = byte & 127;
      // A chunk
      if constexpr (AF32) {
        const float* af = (const float*)Av + (long)z * aZ + (long)(bm * 128 + row) * lda + k0 + (kb >> 1);
        float4 v0 = *(const float4*)af, v1 = *(const float4*)(af + 4);
        s8v va = {f2b(v0.x), f2b(v0.y), f2b(v0.z), f2b(v0.w), f2b(v1.x), f2b(v1.y), f2b(v1.z), f2b(v1.w)};
        *(s8v*)(lab + SW(row, kb)) = va;
      } else {
        s8v va = *(const s8v*)((const char*)Av + ((long)z * aZ + (long)(bm * 128 + row) * lda + k0) * 2 + kb);
        *(s8v*)(lab + SW(row, kb)) = va;
      }
      // B chunk
      if constexpr (BF32) {
        const float* bf_ = (const float*)Bv + (long)z * bZ + (long)(bn * 128 + row) * ldb + k0 + (kb >> 1);
        float4 v0 = *(const float4*)bf_, v1 = *(const float4*)(bf_ + 4);
        s8v vb = {f2b(v0.x), f2b(v0.y), f2b(v0.z), f2b(v0.w), f2b(v1.x), f2b(v1.y), f2b(v1.z), f2b(v1.w)};
        *(s8v*)(lbb + SW(row, kb)) = vb;
      } else {
        s8v vb = *(const s8v*)((const char*)Bv + ((long)z * bZ + (long)(bn * 128 + row) * ldb + k0) * 2 + kb);
        *(s8v*)(lbb + SW(row, kb)) = vb;
      }
    }
    __syncthreads();
#pragma unroll
    for (int ks = 0; ks < 2; ++ks) {
      s8v af[4], bf[4];
      const int kb = ks * 64 + lg * 16;
#pragma unroll
      for (int mi = 0; mi < 4; ++mi) {
        int row = wr * 64 + mi * 16 + lr;
        af[mi] = *(const s8v*)(lab + SW(row, kb));
      }
#pragma unroll
      for (int ni = 0; ni < 4; ++ni) {
        int row = wc * 64 + ni * 16 + lr;
        bf[ni] = *(const s8v*)(lbb + SW(row, kb));
      }
#pragma unroll
      for (int mi = 0; mi < 4; ++mi)
#pragma unroll
        for (int ni = 0; ni < 4; ++ni)
          acc[mi][ni] = __builtin_amdgcn_mfma_f32_16x16x32_bf16(af[mi], bf[ni], acc[mi][ni], 0, 0, 0);
    }
    __syncthreads();
  }

  // epilogue: D row = (l>>4)*4 + r, col = l&15 within each 16x16 frag
#pragma unroll
  for (int mi = 0; mi < 4; ++mi) {
#pragma unroll
    for (int ni = 0; ni < 4; ++ni) {
#pragma unroll
      for (int r = 0; r < 4; ++r) {
        int row = bm * 128 + wr * 64 + mi * 16 + lg * 4 + r;
        int col = bn * 128 + wc * 64 + ni * 16 + lr;
        float v = acc[mi][ni][r];
        if constexpr (EPI == 0) {
          long idx = (long)row * 2048 + col;
          outb16[idx] = f2b(v + b2f(addb16[idx]) + bias[row]);
        } else if constexpr (EPI == 1) {
          long idx = ((long)(z * 2 + (col >> 7)) * 4096 + row) * 128 + (col & 127);
          outb16[idx] = f2b(v + bias[col]);
        } else if constexpr (EPI == 2) {
          long idx = ((long)(z * 256 + row)) * 4096 + col;
          outb16[idx] = f2b(v + bias[row]);
        } else {
          long idx = ((long)(z * 512 + row)) * 4096 + col;
          outf32[idx] = v + bias[row] + addf32[idx];
        }
      }
    }
  }
}

// ---------------- fused flash attention ----------------
// th  [8][4096][128]  (Q, row-major, k fast)
// pht [8][4096][128]  (= phi output transposed: pht[m][dd])
// g   [4][256][4096]  (V in [dd][m] layout)
// yt  [4][4096][256]  (output, [n][head*128+dd])
__global__ __launch_bounds__(256) void attn_k(const us* __restrict__ th,
                                              const us* __restrict__ pht,
                                              const us* __restrict__ g,
                                              us* __restrict__ yt) {
  __shared__ __align__(16) us phtile[64 * 128];   // [m 64][dd 128], swizzled rows of 256B
  __shared__ __align__(16) us gtile[128 * 64];    // [dd 128][m 64], swizzled rows of 128B
  __shared__ __align__(16) us plds[4][16 * 80];   // per-wave P [16 q][64 m], stride 80
  const int tid = threadIdx.x, l = tid & 63, w = tid >> 6;
  const int lr = l & 15, lg = l >> 4;
  const int bh = blockIdx.y, qb = blockIdx.x;
  const int b = bh >> 1, head = bh & 1;
  const float scale = 0.08838834764831845f;  // 1/sqrt(128)
  const f4v zero = {0.f, 0.f, 0.f, 0.f};

  s8v a_th[4];
  {
    const us* thp = th + ((long)bh * 4096 + qb * 64 + w * 16 + lr) * 128 + lg * 8;
#pragma unroll
    for (int ks = 0; ks < 4; ++ks) a_th[ks] = *(const s8v*)(thp + ks * 32);
  }
  f4v acc_y[8];
#pragma unroll
  for (int i = 0; i < 8; ++i) acc_y[i] = zero;
  float m_run[4] = {-1e30f, -1e30f, -1e30f, -1e30f};
  float l_run[4] = {0.f, 0.f, 0.f, 0.f};
  char* phb = (char*)phtile;
  char* gb = (char*)gtile;
  us* pw = &plds[w][0];

  for (int mt = 0; mt < 64; ++mt) {
    const int m0 = mt * 64;
    {  // stage both tiles (reg-staged, swizzled)
      const char* src = (const char*)(pht + ((long)bh * 4096 + m0) * 128);
      const char* srcg = (const char*)(g + ((long)(b * 256 + head * 128) * 4096 + m0));
#pragma unroll
      for (int j = 0; j < 4; ++j) {
        int byte = j * 4096 + tid * 16;
        int row = byte >> 8, kb = byte & 255;
        s8v v = *(const s8v*)(src + row * 256 + kb);
        *(s8v*)(phb + row * 256 + (kb ^ ((row & 7) << 4))) = v;
        int rowg = byte >> 7, kbg = byte & 127;
        s8v vg = *(const s8v*)(srcg + (long)rowg * 8192 + kbg);
        *(s8v*)(gb + SW(rowg, kbg)) = vg;
      }
    }
    __syncthreads();

    // S = th . pht^T  (wave strip: 16 q-rows x 64 m-cols)
    f4v s[4];
#pragma unroll
    for (int ct = 0; ct < 4; ++ct) s[ct] = zero;
#pragma unroll
    for (int ks = 0; ks < 4; ++ks) {
      const int kb = ks * 64 + lg * 16;
#pragma unroll
      for (int ct = 0; ct < 4; ++ct) {
        int row = lr + 16 * ct;
        s8v bfr = *(const s8v*)(phb + row * 256 + (kb ^ ((row & 7) << 4)));
        s[ct] = __builtin_amdgcn_mfma_f32_16x16x32_bf16(a_th[ks], bfr, s[ct], 0, 0, 0);
      }
    }

    // online softmax (rows live in 16-lane groups; reg r -> q-row lg*4+r)
    float mx[4];
#pragma unroll
    for (int r = 0; r < 4; ++r) {
      float a0 = s[0][r] * scale, a1 = s[1][r] * scale;
      float a2 = s[2][r] * scale, a3 = s[3][r] * scale;
      s[0][r] = a0; s[1][r] = a1; s[2][r] = a2; s[3][r] = a3;
      mx[r] = fmaxf(fmaxf(a0, a1), fmaxf(a2, a3));
    }
#pragma unroll
    for (int off = 1; off < 16; off <<= 1)
#pragma unroll
      for (int r = 0; r < 4; ++r) mx[r] = fmaxf(mx[r], __shfl_xor(mx[r], off, 64));
    float corr[4], sm[4];
#pragma unroll
    for (int r = 0; r < 4; ++r) {
      float mn = fmaxf(m_run[r], mx[r]);
      corr[r] = __expf(m_run[r] - mn);
      m_run[r] = mn;
      sm[r] = 0.f;
    }
#pragma unroll
    for (int ct = 0; ct < 4; ++ct)
#pragma unroll
      for (int r = 0; r < 4; ++r) {
        float p = __expf(s[ct][r] - m_run[r]);
        sm[r] += p;
        pw[(lg * 4 + r) * 80 + lr + 16 * ct] = f2b(p);
      }
#pragma unroll
    for (int off = 1; off < 16; off <<= 1)
#pragma unroll
      for (int r = 0; r < 4; ++r) sm[r] += __shfl_xor(sm[r], off, 64);
#pragma unroll
    for (int r = 0; r < 4; ++r) l_run[r] = l_run[r] * corr[r] + sm[r];
#pragma unroll
    for (int dt = 0; dt < 8; ++dt) {
      f4v t = acc_y[dt];
      t[0] *= corr[0]; t[1] *= corr[1]; t[2] *= corr[2]; t[3] *= corr[3];
      acc_y[dt] = t;
    }

    // PV: y[16 q][128 dd] += P[16 q][64 m] . g[64 m][128 dd]
#pragma unroll
    for (int ks2 = 0; ks2 < 2; ++ks2) {
      s8v ap = *(const s8v*)(pw + lr * 80 + ks2 * 32 + lg * 8);
      const int kb = ks2 * 64 + lg * 16;
#pragma unroll
      for (int dt = 0; dt < 8; ++dt) {
        int row = lr + 16 * dt;
        s8v bg = *(const s8v*)(gb + SW(row, kb));
        acc_y[dt] = __builtin_amdgcn_mfma_f32_16x16x32_bf16(ap, bg, acc_y[dt], 0, 0, 0);
      }
    }
    __syncthreads();
  }

  // epilogue: yt[b][n][head*128+dd] = y/l
#pragma unroll
  for (int r = 0; r < 4; ++r) {
    float inv = 1.0f / l_run[r];
    long n = (long)qb * 64 + w * 16 + lg * 4 + r;
    us* dst = yt + ((long)b * 4096 + n) * 256 + head * 128 + lr;
#pragma unroll
    for (int dt = 0; dt < 8; ++dt) dst[dt * 16] = f2b(acc_y[dt][r] * inv);
  }
}

extern "C" void kernel_launch(void* const* d_in, const int* in_sizes, int n_in,
                              void* d_out, int out_size, void* d_ws, size_t ws_size,
                              hipStream_t stream) {
  (void)in_sizes; (void)n_in; (void)out_size; (void)ws_size;
  const float* x       = (const float*)d_in[0];
  const float* oa      = (const float*)d_in[1];
  const float* mlp_w   = (const float*)d_in[2];
  const float* mlp_b   = (const float*)d_in[3];
  const float* g_w     = (const float*)d_in[4];
  const float* g_b     = (const float*)d_in[5];
  const float* theta_w = (const float*)d_in[6];
  const float* theta_b = (const float*)d_in[7];
  const float* phi_w   = (const float*)d_in[8];
  const float* phi_b   = (const float*)d_in[9];
  const float* out_w   = (const float*)d_in[10];
  const float* out_b   = (const float*)d_in[11];
  float* out = (float*)d_out;
  char* ws = (char*)d_ws;

  // workspace layout (bytes); xt is dead after the MLP GEMM, g/th/ph/yt alias past it
  us* xf_t   = (us*)(ws + 0L);          // [4096][2048] bf16 : xf transposed (spatial-major)
  us* oat    = (us*)(ws + 16777216L);   // [4096][2048] bf16 : output_attn transposed
  us* xt     = (us*)(ws + 33554432L);   // [4096][2048] bf16 : x transposed (MLP epilogue add)
  us* g_ws   = (us*)(ws + 33554432L);   // [4][256][4096] bf16 (aliases xt)
  us* th_ws  = (us*)(ws + 41943040L);   // [8][4096][128] bf16
  us* ph_ws  = (us*)(ws + 50331648L);   // [8][4096][128] bf16
  us* yt     = (us*)(ws + 58720256L);   // [4][4096][256] bf16
  us* g_wb   = (us*)(ws + 67108864L);
  us* th_wb  = (us*)(ws + 67371008L);
  us* ph_wb  = (us*)(ws + 67633152L);
  us* out_wb = (us*)(ws + 67895296L);   // end ~65 MiB

  // weight casts
  castk<<<dim3(128), dim3(256), 0, stream>>>(g_w, g_wb, 32768);
  castk<<<dim3(128), dim3(256), 0, stream>>>(theta_w, th_wb, 32768);
  castk<<<dim3(128), dim3(256), 0, stream>>>(phi_w, ph_wb, 32768);
  castk<<<dim3(128), dim3(256), 0, stream>>>(out_w, out_wb, 32768);
  // transposes
  tcast<<<dim3(64, 32), dim3(256), 0, stream>>>(x, xt, 2048, 4096);
  tcast<<<dim3(64, 32), dim3(256), 0, stream>>>(oa, oat, 2048, 4096);

  // MLP remix (fp32 operands converted during staging):
  // xf_t[m][r] = sum_n mlp_w[m][n]*x[r][n] + x[r][m] + mlp_b[m]
  gemm_nt<0, 1, 1><<<dim3(32, 16, 1), dim3(256), 0, stream>>>(
      mlp_w, x, 4096, 4096, 4096, 0, 0, mlp_b, xt, nullptr, xf_t, nullptr);

  // theta: th_ws[bh][n][dd] = sum_c oat[n][b*512+c]*theta_w[o][c] + theta_b[o]
  gemm_nt<1, 0, 0><<<dim3(32, 2, 4), dim3(256), 0, stream>>>(
      oat, th_wb, 2048, 512, 512, 512, 0, theta_b, nullptr, nullptr, th_ws, nullptr);
  // phi (transposed layout): ph_ws[bh][m][dd]
  gemm_nt<1, 0, 0><<<dim3(32, 2, 4), dim3(256), 0, stream>>>(
      xf_t, ph_wb, 2048, 512, 512, 512, 0, phi_b, nullptr, nullptr, ph_ws, nullptr);
  // g: g_ws[b][o][n]
  gemm_nt<2, 0, 0><<<dim3(2, 32, 4), dim3(256), 0, stream>>>(
      g_wb, xf_t, 512, 2048, 512, 0, 512, g_b, nullptr, nullptr, g_ws, nullptr);

  // fused softmax attention
  attn_k<<<dim3(64, 8), dim3(256), 0, stream>>>(th_ws, ph_ws, g_ws, yt);

  // final conv + residual: out[b][c][n] = oa + sum_o out_w[c][o]*yt[b][n][o] + out_b[c]
  gemm_nt<3, 0, 0><<<dim3(4, 32, 4), dim3(256), 0, stream>>>(
      out_wb, yt, 256, 256, 256, 0, 1048576L, out_b, nullptr, oa, nullptr, out);
}

// Round 2
// 356.196 us; speedup vs baseline: 1.5431x; 1.5431x over previous
//
#include <hip/hip_runtime.h>

typedef unsigned short us;
typedef us s8v __attribute__((ext_vector_type(8)));   // 8 bf16 (4 VGPRs)
typedef us s4v __attribute__((ext_vector_type(4)));
typedef float f4v __attribute__((ext_vector_type(4)));

static __device__ __forceinline__ us f2b(float f) {
  unsigned u = __builtin_bit_cast(unsigned, f);
  return (us)((u + 0x7fffu + ((u >> 16) & 1u)) >> 16);   // RNE fp32->bf16
}
static __device__ __forceinline__ float b2f(us s) {
  unsigned u = ((unsigned)s) << 16;
  return __builtin_bit_cast(float, u);
}

// ---------------- flat f32 -> bf16 cast ----------------
__global__ __launch_bounds__(256) void castk(const float* __restrict__ in,
                                             us* __restrict__ out, int n4) {
  int i = blockIdx.x * 256 + threadIdx.x;
  int stride = gridDim.x * 256;
  for (; i < n4; i += stride) {
    float4 v = ((const float4*)in)[i];
    s4v s = {f2b(v.x), f2b(v.y), f2b(v.z), f2b(v.w)};
    ((s4v*)out)[i] = s;
  }
}

// ---------------- transpose-cast: f32 [R][C] -> bf16 [C][R] ----------------
__global__ __launch_bounds__(256) void tcast(const float* __restrict__ in,
                                             us* __restrict__ out, int R, int C) {
  __shared__ float t[64][65];
  const int tid = threadIdx.x;
  const long r0 = (long)blockIdx.y * 64, c0 = (long)blockIdx.x * 64;
#pragma unroll
  for (int j = 0; j < 4; ++j) {
    int idx = j * 256 + tid;
    int row = idx >> 4, c4 = (idx & 15) * 4;
    float4 v = *(const float4*)(in + (r0 + row) * C + c0 + c4);
    t[row][c4] = v.x; t[row][c4 + 1] = v.y; t[row][c4 + 2] = v.z; t[row][c4 + 3] = v.w;
  }
  __syncthreads();
#pragma unroll
  for (int j = 0; j < 4; ++j) {
    int idx = j * 256 + tid;
    int orow = idx >> 4, r4 = (idx & 15) * 4;
    s4v s = {f2b(t[r4][orow]), f2b(t[r4 + 1][orow]), f2b(t[r4 + 2][orow]), f2b(t[r4 + 3][orow])};
    *(s4v*)(out + (c0 + orow) * R + r0 + r4) = s;
  }
}

// byte-offset into a [rows][128 B] LDS tile, XOR-swizzled (T2)
#define SW(row, kb) ((row) * 128 + ((kb) ^ (((row) & 7) << 4)))

// ---------------- generic NT bf16 MFMA GEMM, 128x128 tile, BK=64 ----------------
// C[row][col] = sum_k A[row][k] * B[col][k]  (+ epilogue)
// EPI 0: out_b16[row*2048+col] = v + b2f(addb16[same]) + bias[row]        (MLP -> xf_t)
// EPI 1: out_b16[((z*2+(col>>7))*4096+row)*128+(col&127)] = v + bias[col] (theta/phi -> [bh][n][d])
// EPI 2: out_b16[(z*256+row)*4096+col] = v + bias[row]                    (g -> [b][IC][n])
// EPI 3: outf32[(z*512+row)*4096+col] = v + bias[row] + addf32[same]      (final output)
template <int EPI, int AF32, int BF32>
__global__ __launch_bounds__(256) void gemm_nt(
    const void* __restrict__ Av, const void* __restrict__ Bv,
    int lda, int ldb, int K, long aZ, long bZ,
    const float* __restrict__ bias,
    const us* __restrict__ addb16,
    const float* __restrict__ addf32,
    us* __restrict__ outb16,
    float* __restrict__ outf32) {
  __shared__ __align__(16) us lA[128 * 64];
  __shared__ __align__(16) us lB[128 * 64];
  const int tid = threadIdx.x, l = tid & 63;
  const int lr = l & 15, lg = l >> 4;
  const int w = tid >> 6, wr = w >> 1, wc = w & 1;
  const int bm = blockIdx.x, bn = blockIdx.y, z = blockIdx.z;
  const f4v zero = {0.f, 0.f, 0.f, 0.f};
  f4v acc[4][4];
#pragma unroll
  for (int i = 0; i < 4; ++i)
#pragma unroll
    for (int j = 0; j < 4; ++j) acc[i][j] = zero;
  char* lab = (char*)lA;
  char* lbb = (char*)lB;

  for (int k0 = 0; k0 < K; k0 += 64) {
#pragma unroll
    for (int j = 0; j < 4; ++j) {
      int byte = j * 4096 + tid * 16;
      int row = byte >> 7, kb = byte & 127;
      // A chunk
      if constexpr (AF32) {
        const float* af = (const float*)Av + (long)z * aZ + (long)(bm * 128 + row) * lda + k0 + (kb >> 1);
        float4 v0 = *(const float4*)af, v1 = *(const float4*)(af + 4);
        s8v va = {f2b(v0.x), f2b(v0.y), f2b(v0.z), f2b(v0.w), f2b(v1.x), f2b(v1.y), f2b(v1.z), f2b(v1.w)};
        *(s8v*)(lab + SW(row, kb)) = va;
      } else {
        s8v va = *(const s8v*)((const char*)Av + ((long)z * aZ + (long)(bm * 128 + row) * lda + k0) * 2 + kb);
        *(s8v*)(lab + SW(row, kb)) = va;
      }
      // B chunk
      if constexpr (BF32) {
        const float* bf_ = (const float*)Bv + (long)z * bZ + (long)(bn * 128 + row) * ldb + k0 + (kb >> 1);
        float4 v0 = *(const float4*)bf_, v1 = *(const float4*)(bf_ + 4);
        s8v vb = {f2b(v0.x), f2b(v0.y), f2b(v0.z), f2b(v0.w), f2b(v1.x), f2b(v1.y), f2b(v1.z), f2b(v1.w)};
        *(s8v*)(lbb + SW(row, kb)) = vb;
      } else {
        s8v vb = *(const s8v*)((const char*)Bv + ((long)z * bZ + (long)(bn * 128 + row) * ldb + k0) * 2 + kb);
        *(s8v*)(lbb + SW(row, kb)) = vb;
      }
    }
    __syncthreads();
#pragma unroll
    for (int ks = 0; ks < 2; ++ks) {
      s8v af[4], bf[4];
      const int kb = ks * 64 + lg * 16;
#pragma unroll
      for (int mi = 0; mi < 4; ++mi) {
        int row = wr * 64 + mi * 16 + lr;
        af[mi] = *(const s8v*)(lab + SW(row, kb));
      }
#pragma unroll
      for (int ni = 0; ni < 4; ++ni) {
        int row = wc * 64 + ni * 16 + lr;
        bf[ni] = *(const s8v*)(lbb + SW(row, kb));
      }
#pragma unroll
      for (int mi = 0; mi < 4; ++mi)
#pragma unroll
        for (int ni = 0; ni < 4; ++ni)
          acc[mi][ni] = __builtin_amdgcn_mfma_f32_16x16x32_bf16(af[mi], bf[ni], acc[mi][ni], 0, 0, 0);
    }
    __syncthreads();
  }

  // epilogue: D row = (l>>4)*4 + r, col = l&15 within each 16x16 frag
#pragma unroll
  for (int mi = 0; mi < 4; ++mi) {
#pragma unroll
    for (int ni = 0; ni < 4; ++ni) {
#pragma unroll
      for (int r = 0; r < 4; ++r) {
        int row = bm * 128 + wr * 64 + mi * 16 + lg * 4 + r;
        int col = bn * 128 + wc * 64 + ni * 16 + lr;
        float v = acc[mi][ni][r];
        if constexpr (EPI == 0) {
          long idx = (long)row * 2048 + col;
          outb16[idx] = f2b(v + b2f(addb16[idx]) + bias[row]);
        } else if constexpr (EPI == 1) {
          long idx = ((long)(z * 2 + (col >> 7)) * 4096 + row) * 128 + (col & 127);
          outb16[idx] = f2b(v + bias[col]);
        } else if constexpr (EPI == 2) {
          long idx = ((long)(z * 256 + row)) * 4096 + col;
          outb16[idx] = f2b(v + bias[row]);
        } else {
          long idx = ((long)(z * 512 + row)) * 4096 + col;
          outf32[idx] = v + bias[row] + addf32[idx];
        }
      }
    }
  }
}

// ---------------- fused flash attention (double-buffered, 1 barrier/iter) --------
// th  [8][4096][128]  (Q, row-major)
// pht [8][4096][128]  (K rows)
// g   [4][256][4096]  (V in [dd][m] layout)
// yt  [4][4096][256]  (output, [n][head*128+dd])
__global__ __launch_bounds__(256) void attn_k(const us* __restrict__ th,
                                              const us* __restrict__ pht,
                                              const us* __restrict__ g,
                                              us* __restrict__ yt) {
  __shared__ __align__(16) us ph2[2][64 * 128];   // K tiles [m 64][dd 128], 256B rows swizzled
  __shared__ __align__(16) us g2[2][128 * 64];    // V tiles [dd 128][m 64], 128B rows swizzled
  __shared__ __align__(16) us plds[4][1024];      // per-wave P [16 q][64 m], 128B rows swizzled
  const int tid = threadIdx.x, l = tid & 63, w = tid >> 6;
  const int lr = l & 15, lg = l >> 4;
  const int bh = blockIdx.y, qb = blockIdx.x;
  const int b = bh >> 1, head = bh & 1;
  const float scale = 0.08838834764831845f;  // 1/sqrt(128)
  const f4v zero = {0.f, 0.f, 0.f, 0.f};

  const char* phsrc = (const char*)(pht + (long)bh * 4096 * 128);
  const char* gsrc = (const char*)(g + (long)(b * 256 + head * 128) * 4096);

  s8v a_th[4];
  {
    const us* thp = th + ((long)bh * 4096 + qb * 64 + w * 16 + lr) * 128 + lg * 8;
#pragma unroll
    for (int ks = 0; ks < 4; ++ks) a_th[ks] = *(const s8v*)(thp + ks * 32);
  }
  f4v acc_y[8];
#pragma unroll
  for (int i = 0; i < 8; ++i) acc_y[i] = zero;
  float m_run[4] = {-1e30f, -1e30f, -1e30f, -1e30f};
  float l_run[4] = {0.f, 0.f, 0.f, 0.f};
  char* pw = (char*)&plds[w][0];
  const int byte0 = tid * 16;
  s8v rp[4], rg[4];

  auto load_t = [&](int m0) {
    const char* sp = phsrc + (long)m0 * 256;
    const char* sg = gsrc + (long)m0 * 2;
#pragma unroll
    for (int j = 0; j < 4; ++j) {
      int byte = j * 4096 + byte0;
      rp[j] = *(const s8v*)(sp + byte);
      rg[j] = *(const s8v*)(sg + (long)(byte >> 7) * 8192 + (byte & 127));
    }
  };
  auto store_t = [&](int bufi) {
    char* dp = (char*)ph2[bufi];
    char* dg = (char*)g2[bufi];
#pragma unroll
    for (int j = 0; j < 4; ++j) {
      int byte = j * 4096 + byte0;
      int row = byte >> 8, kb = byte & 255;
      *(s8v*)(dp + row * 256 + (kb ^ ((row & 7) << 4))) = rp[j];
      int rowg = byte >> 7, kbg = byte & 127;
      *(s8v*)(dg + SW(rowg, kbg)) = rg[j];
    }
  };

  load_t(0);
  store_t(0);
  __syncthreads();

  for (int mt = 0; mt < 64; ++mt) {
    const int cur = mt & 1;
    load_t(((mt + 1) & 63) * 64);  // issue next tile's loads; land under compute
    const char* phb = (const char*)ph2[cur];
    const char* gb = (const char*)g2[cur];

    // S = th . pht^T  (wave strip: 16 q-rows x 64 m-cols)
    f4v s[4];
#pragma unroll
    for (int ct = 0; ct < 4; ++ct) s[ct] = zero;
    __builtin_amdgcn_s_setprio(1);
#pragma unroll
    for (int ks = 0; ks < 4; ++ks) {
      const int kb = ks * 64 + lg * 16;
#pragma unroll
      for (int ct = 0; ct < 4; ++ct) {
        int row = lr + 16 * ct;
        s8v bfr = *(const s8v*)(phb + row * 256 + (kb ^ ((row & 7) << 4)));
        s[ct] = __builtin_amdgcn_mfma_f32_16x16x32_bf16(a_th[ks], bfr, s[ct], 0, 0, 0);
      }
    }
    __builtin_amdgcn_s_setprio(0);

    // online softmax (rows live in 16-lane groups; reg r -> q-row lg*4+r)
    float mx[4];
#pragma unroll
    for (int r = 0; r < 4; ++r) {
      float a0 = s[0][r] * scale, a1 = s[1][r] * scale;
      float a2 = s[2][r] * scale, a3 = s[3][r] * scale;
      s[0][r] = a0; s[1][r] = a1; s[2][r] = a2; s[3][r] = a3;
      mx[r] = fmaxf(fmaxf(a0, a1), fmaxf(a2, a3));
    }
#pragma unroll
    for (int off = 1; off < 16; off <<= 1)
#pragma unroll
      for (int r = 0; r < 4; ++r) mx[r] = fmaxf(mx[r], __shfl_xor(mx[r], off, 64));
    // defer-max (T13): only rescale when the running max grew by > 8
    int need = 0;
#pragma unroll
    for (int r = 0; r < 4; ++r) need |= (mx[r] > m_run[r] + 8.0f) ? 1 : 0;
    if (__any(need)) {
#pragma unroll
      for (int r = 0; r < 4; ++r) {
        float mn = fmaxf(m_run[r], mx[r]);
        float corr = __expf(m_run[r] - mn);
        m_run[r] = mn;
        l_run[r] *= corr;
#pragma unroll
        for (int dt = 0; dt < 8; ++dt) acc_y[dt][r] *= corr;
      }
    }
    float sm[4] = {0.f, 0.f, 0.f, 0.f};
#pragma unroll
    for (int ct = 0; ct < 4; ++ct)
#pragma unroll
      for (int r = 0; r < 4; ++r) {
        float p = __expf(s[ct][r] - m_run[r]);
        sm[r] += p;
        int q = lg * 4 + r;
        *(us*)(pw + q * 128 + ((2 * (lr + 16 * ct)) ^ ((q & 7) << 4))) = f2b(p);
      }
#pragma unroll
    for (int off = 1; off < 16; off <<= 1)
#pragma unroll
      for (int r = 0; r < 4; ++r) sm[r] += __shfl_xor(sm[r], off, 64);
#pragma unroll
    for (int r = 0; r < 4; ++r) l_run[r] += sm[r];

    // PV: y[16 q][128 dd] += P[16 q][64 m] . g[64 m][128 dd]
#pragma unroll
    for (int ks2 = 0; ks2 < 2; ++ks2) {
      const int kb = ks2 * 64 + lg * 16;
      s8v ap = *(const s8v*)(pw + lr * 128 + (kb ^ ((lr & 7) << 4)));
      __builtin_amdgcn_s_setprio(1);
#pragma unroll
      for (int dt = 0; dt < 8; ++dt) {
        int row = lr + 16 * dt;
        s8v bg = *(const s8v*)(gb + SW(row, kb));
        acc_y[dt] = __builtin_amdgcn_mfma_f32_16x16x32_bf16(ap, bg, acc_y[dt], 0, 0, 0);
      }
      __builtin_amdgcn_s_setprio(0);
    }

    store_t(cur ^ 1);   // write next tile into the other buffer
    __syncthreads();    // one barrier per iteration
  }

  // epilogue: yt[b][n][head*128+dd] = y/l
#pragma unroll
  for (int r = 0; r < 4; ++r) {
    float inv = 1.0f / l_run[r];
    long n = (long)qb * 64 + w * 16 + lg * 4 + r;
    us* dst = yt + ((long)b * 4096 + n) * 256 + head * 128 + lr;
#pragma unroll
    for (int dt = 0; dt < 8; ++dt) dst[dt * 16] = f2b(acc_y[dt][r] * inv);
  }
}

extern "C" void kernel_launch(void* const* d_in, const int* in_sizes, int n_in,
                              void* d_out, int out_size, void* d_ws, size_t ws_size,
                              hipStream_t stream) {
  (void)in_sizes; (void)n_in; (void)out_size; (void)ws_size;
  const float* x       = (const float*)d_in[0];
  const float* oa      = (const float*)d_in[1];
  const float* mlp_w   = (const float*)d_in[2];
  const float* mlp_b   = (const float*)d_in[3];
  const float* g_w     = (const float*)d_in[4];
  const float* g_b     = (const float*)d_in[5];
  const float* theta_w = (const float*)d_in[6];
  const float* theta_b = (const float*)d_in[7];
  const float* phi_w   = (const float*)d_in[8];
  const float* phi_b   = (const float*)d_in[9];
  const float* out_w   = (const float*)d_in[10];
  const float* out_b   = (const float*)d_in[11];
  float* out = (float*)d_out;
  char* ws = (char*)d_ws;

  // workspace layout (bytes); xt/xc die after the MLP GEMM, g/th/ph/yt alias past them
  us* xf_t   = (us*)(ws + 0L);          // [4096][2048] bf16 : xf transposed (spatial-major)
  us* oat    = (us*)(ws + 16777216L);   // [4096][2048] bf16 : output_attn transposed
  us* xt     = (us*)(ws + 33554432L);   // [4096][2048] bf16 : x transposed (MLP epilogue add)
  us* g_ws   = (us*)(ws + 33554432L);   // [4][256][4096] bf16 (aliases xt)
  us* th_ws  = (us*)(ws + 41943040L);   // [8][4096][128] bf16
  us* xc     = (us*)(ws + 50331648L);   // [2048][4096] bf16 : x cast (MLP B operand)
  us* ph_ws  = (us*)(ws + 50331648L);   // [8][4096][128] bf16 (aliases xc, written after MLP)
  us* yt     = (us*)(ws + 58720256L);   // [4][4096][256] bf16
  us* g_wb   = (us*)(ws + 67108864L);
  us* th_wb  = (us*)(ws + 67371008L);
  us* ph_wb  = (us*)(ws + 67633152L);
  us* out_wb = (us*)(ws + 67895296L);   // end ~65 MiB

  // weight casts
  castk<<<dim3(128), dim3(256), 0, stream>>>(g_w, g_wb, 32768);
  castk<<<dim3(128), dim3(256), 0, stream>>>(theta_w, th_wb, 32768);
  castk<<<dim3(128), dim3(256), 0, stream>>>(phi_w, ph_wb, 32768);
  castk<<<dim3(128), dim3(256), 0, stream>>>(out_w, out_wb, 32768);
  // x cast (for MLP B side) + transposes
  castk<<<dim3(1024), dim3(256), 0, stream>>>(x, xc, 2097152);
  tcast<<<dim3(64, 32), dim3(256), 0, stream>>>(x, xt, 2048, 4096);
  tcast<<<dim3(64, 32), dim3(256), 0, stream>>>(oa, oat, 2048, 4096);

  // MLP remix: xf_t[m][r] = sum_n mlp_w[m][n]*x[r][n] + x[r][m] + mlp_b[m]
  gemm_nt<0, 1, 0><<<dim3(32, 16, 1), dim3(256), 0, stream>>>(
      mlp_w, xc, 4096, 4096, 4096, 0, 0, mlp_b, xt, nullptr, xf_t, nullptr);

  // theta: th_ws[bh][n][dd] = sum_c oat[n][b*512+c]*theta_w[o][c] + theta_b[o]
  gemm_nt<1, 0, 0><<<dim3(32, 2, 4), dim3(256), 0, stream>>>(
      oat, th_wb, 2048, 512, 512, 512, 0, theta_b, nullptr, nullptr, th_ws, nullptr);
  // phi (transposed layout): ph_ws[bh][m][dd]
  gemm_nt<1, 0, 0><<<dim3(32, 2, 4), dim3(256), 0, stream>>>(
      xf_t, ph_wb, 2048, 512, 512, 512, 0, phi_b, nullptr, nullptr, ph_ws, nullptr);
  // g: g_ws[b][o][n]
  gemm_nt<2, 0, 0><<<dim3(2, 32, 4), dim3(256), 0, stream>>>(
      g_wb, xf_t, 512, 2048, 512, 0, 512, g_b, nullptr, nullptr, g_ws, nullptr);

  // fused softmax attention
  attn_k<<<dim3(64, 8), dim3(256), 0, stream>>>(th_ws, ph_ws, g_ws, yt);

  // final conv + residual: out[b][c][n] = oa + sum_o out_w[c][o]*yt[b][n][o] + out_b[c]
  gemm_nt<3, 0, 0><<<dim3(4, 32, 4), dim3(256), 0, stream>>>(
      out_wb, yt, 256, 256, 256, 0, 1048576L, out_b, nullptr, oa, nullptr, out);
}

// Round 3
// 312.058 us; speedup vs baseline: 1.7613x; 1.1414x over previous
//
#include <hip/hip_runtime.h>

typedef unsigned short us;
typedef us s8v __attribute__((ext_vector_type(8)));   // 8 bf16 (4 VGPRs)
typedef us s4v __attribute__((ext_vector_type(4)));
typedef float f4v __attribute__((ext_vector_type(4)));

static __device__ __forceinline__ us f2b(float f) {
  unsigned u = __builtin_bit_cast(unsigned, f);
  return (us)((u + 0x7fffu + ((u >> 16) & 1u)) >> 16);   // RNE fp32->bf16
}
static __device__ __forceinline__ float b2f(us s) {
  unsigned u = ((unsigned)s) << 16;
  return __builtin_bit_cast(float, u);
}

// ---------------- flat f32 -> bf16 cast ----------------
__global__ __launch_bounds__(256) void castk(const float* __restrict__ in,
                                             us* __restrict__ out, int n4) {
  int i = blockIdx.x * 256 + threadIdx.x;
  int stride = gridDim.x * 256;
  for (; i < n4; i += stride) {
    float4 v = ((const float4*)in)[i];
    s4v s = {f2b(v.x), f2b(v.y), f2b(v.z), f2b(v.w)};
    ((s4v*)out)[i] = s;
  }
}

// 4 weight casts in one launch (each 131072 f32 -> bf16)
__global__ __launch_bounds__(256) void wcast4(const float* __restrict__ s0, us* __restrict__ o0,
                                              const float* __restrict__ s1, us* __restrict__ o1,
                                              const float* __restrict__ s2, us* __restrict__ o2,
                                              const float* __restrict__ s3, us* __restrict__ o3) {
  const float* s; us* o;
  int y = blockIdx.y;
  if (y == 0) { s = s0; o = o0; }
  else if (y == 1) { s = s1; o = o1; }
  else if (y == 2) { s = s2; o = o2; }
  else { s = s3; o = o3; }
  int i = blockIdx.x * 256 + threadIdx.x;
  for (; i < 32768; i += 8192) {
    float4 v = ((const float4*)s)[i];
    s4v r = {f2b(v.x), f2b(v.y), f2b(v.z), f2b(v.w)};
    ((s4v*)o)[i] = r;
  }
}

// ---------------- transpose-cast: f32 [R][C] -> bf16 [C][R] ----------------
__global__ __launch_bounds__(256) void tcast(const float* __restrict__ in,
                                             us* __restrict__ out, int R, int C) {
  __shared__ float t[64][65];
  const int tid = threadIdx.x;
  const long r0 = (long)blockIdx.y * 64, c0 = (long)blockIdx.x * 64;
#pragma unroll
  for (int j = 0; j < 4; ++j) {
    int idx = j * 256 + tid;
    int row = idx >> 4, c4 = (idx & 15) * 4;
    float4 v = *(const float4*)(in + (r0 + row) * C + c0 + c4);
    t[row][c4] = v.x; t[row][c4 + 1] = v.y; t[row][c4 + 2] = v.z; t[row][c4 + 3] = v.w;
  }
  __syncthreads();
#pragma unroll
  for (int j = 0; j < 4; ++j) {
    int idx = j * 256 + tid;
    int orow = idx >> 4, r4 = (idx & 15) * 4;
    s4v s = {f2b(t[r4][orow]), f2b(t[r4 + 1][orow]), f2b(t[r4 + 2][orow]), f2b(t[r4 + 3][orow])};
    *(s4v*)(out + (c0 + orow) * R + r0 + r4) = s;
  }
}

// byte-offset into a [rows][128 B] LDS tile, XOR-swizzled (T2)
#define SW(row, kb) ((row) * 128 + ((kb) ^ (((row) & 7) << 4)))

// ---------------- generic NT bf16 MFMA GEMM, 128x128 tile, BK=64 ----------------
// C[row][col] = sum_k A[row][k] * B[col][k]  (+ epilogue)
template <int EPI, int AF32, int BF32, int SWZ>
__global__ __launch_bounds__(256) void gemm_nt(
    const void* __restrict__ Av, const void* __restrict__ Bv,
    int lda, int ldb, int K, long aZ, long bZ,
    const float* __restrict__ bias,
    const us* __restrict__ addb16,
    const float* __restrict__ addf32,
    us* __restrict__ outb16,
    float* __restrict__ outf32) {
  __shared__ __align__(16) us lA[128 * 64];
  __shared__ __align__(16) us lB[128 * 64];
  const int tid = threadIdx.x, l = tid & 63;
  const int lr = l & 15, lg = l >> 4;
  const int w = tid >> 6, wr = w >> 1, wc = w & 1;
  int bm, bn;
  if constexpr (SWZ) {   // XCD-contiguous remap (requires nwg % 8 == 0)
    int flat = blockIdx.y * gridDim.x + blockIdx.x;
    int re = (flat & 7) * ((gridDim.x * gridDim.y) >> 3) + (flat >> 3);
    bm = re % gridDim.x; bn = re / gridDim.x;
  } else { bm = blockIdx.x; bn = blockIdx.y; }
  const int z = blockIdx.z;
  const f4v zero = {0.f, 0.f, 0.f, 0.f};
  f4v acc[4][4];
#pragma unroll
  for (int i = 0; i < 4; ++i)
#pragma unroll
    for (int j = 0; j < 4; ++j) acc[i][j] = zero;
  char* lab = (char*)lA;
  char* lbb = (char*)lB;

  for (int k0 = 0; k0 < K; k0 += 64) {
#pragma unroll
    for (int j = 0; j < 4; ++j) {
      int byte = j * 4096 + tid * 16;
      int row = byte >> 7, kb = byte & 127;
      if constexpr (AF32) {
        const float* af = (const float*)Av + (long)z * aZ + (long)(bm * 128 + row) * lda + k0 + (kb >> 1);
        float4 v0 = *(const float4*)af, v1 = *(const float4*)(af + 4);
        s8v va = {f2b(v0.x), f2b(v0.y), f2b(v0.z), f2b(v0.w), f2b(v1.x), f2b(v1.y), f2b(v1.z), f2b(v1.w)};
        *(s8v*)(lab + SW(row, kb)) = va;
      } else {
        s8v va = *(const s8v*)((const char*)Av + ((long)z * aZ + (long)(bm * 128 + row) * lda + k0) * 2 + kb);
        *(s8v*)(lab + SW(row, kb)) = va;
      }
      if constexpr (BF32) {
        const float* bf_ = (const float*)Bv + (long)z * bZ + (long)(bn * 128 + row) * ldb + k0 + (kb >> 1);
        float4 v0 = *(const float4*)bf_, v1 = *(const float4*)(bf_ + 4);
        s8v vb = {f2b(v0.x), f2b(v0.y), f2b(v0.z), f2b(v0.w), f2b(v1.x), f2b(v1.y), f2b(v1.z), f2b(v1.w)};
        *(s8v*)(lbb + SW(row, kb)) = vb;
      } else {
        s8v vb = *(const s8v*)((const char*)Bv + ((long)z * bZ + (long)(bn * 128 + row) * ldb + k0) * 2 + kb);
        *(s8v*)(lbb + SW(row, kb)) = vb;
      }
    }
    __syncthreads();
#pragma unroll
    for (int ks = 0; ks < 2; ++ks) {
      s8v af[4], bf[4];
      const int kb = ks * 64 + lg * 16;
#pragma unroll
      for (int mi = 0; mi < 4; ++mi) {
        int row = wr * 64 + mi * 16 + lr;
        af[mi] = *(const s8v*)(lab + SW(row, kb));
      }
#pragma unroll
      for (int ni = 0; ni < 4; ++ni) {
        int row = wc * 64 + ni * 16 + lr;
        bf[ni] = *(const s8v*)(lbb + SW(row, kb));
      }
#pragma unroll
      for (int mi = 0; mi < 4; ++mi)
#pragma unroll
        for (int ni = 0; ni < 4; ++ni)
          acc[mi][ni] = __builtin_amdgcn_mfma_f32_16x16x32_bf16(af[mi], bf[ni], acc[mi][ni], 0, 0, 0);
    }
    __syncthreads();
  }

#pragma unroll
  for (int mi = 0; mi < 4; ++mi) {
#pragma unroll
    for (int ni = 0; ni < 4; ++ni) {
#pragma unroll
      for (int r = 0; r < 4; ++r) {
        int row = bm * 128 + wr * 64 + mi * 16 + lg * 4 + r;
        int col = bn * 128 + wc * 64 + ni * 16 + lr;
        float v = acc[mi][ni][r];
        if constexpr (EPI == 0) {
          long idx = (long)row * 2048 + col;
          outb16[idx] = f2b(v + b2f(addb16[idx]) + bias[row]);
        } else if constexpr (EPI == 1) {
          long idx = ((long)(z * 2 + (col >> 7)) * 4096 + row) * 128 + (col & 127);
          outb16[idx] = f2b(v + bias[col]);
        } else if constexpr (EPI == 2) {
          long idx = ((long)(z * 256 + row)) * 4096 + col;
          outb16[idx] = f2b(v + bias[row]);
        } else {
          long idx = ((long)(z * 512 + row)) * 4096 + col;
          outf32[idx] = v + bias[row] + addf32[idx];
        }
      }
    }
  }
}

// ---------------- fused flash attention (swapped QK^T, in-register softmax) ------
// th  [8][4096][128]  (Q)   pht [8][4096][128] (K)
// g   [4][256][4096]  (V, [dd][m])   yt [4][4096][256]
__global__ __launch_bounds__(256) void attn_k(const us* __restrict__ th,
                                              const us* __restrict__ pht,
                                              const us* __restrict__ g,
                                              us* __restrict__ yt) {
  __shared__ __align__(16) us ph2[2][64 * 128];   // K tiles [m 64][dd 128]
  __shared__ __align__(16) us g2[2][128 * 64];    // V tiles [dd 128][m 64]
  __shared__ __align__(16) us plds[4][1024];      // per-wave P [16 q][64 m]
  const int tid = threadIdx.x, l = tid & 63, w = tid >> 6;
  const int lr = l & 15, lg = l >> 4;
  const int flat = blockIdx.y * 64 + blockIdx.x;
  const int bh = flat & 7, qb = flat >> 3;        // XCD c <- bh c : K/V L2-resident
  const int b = bh >> 1, head = bh & 1;
  const float C1 = 0.12751802f;                   // (1/sqrt(128)) * log2(e)
  const f4v zero = {0.f, 0.f, 0.f, 0.f};

  const char* phsrc = (const char*)(pht + (long)bh * 4096 * 128);
  const char* gsrc = (const char*)(g + (long)(b * 256 + head * 128) * 4096);

  s8v a_th[4];   // Q rows w*16+lr, k = ks*32 + lg*8 .. +7  (B-operand)
  {
    const us* thp = th + ((long)bh * 4096 + qb * 64 + w * 16 + lr) * 128 + lg * 8;
#pragma unroll
    for (int ks = 0; ks < 4; ++ks) a_th[ks] = *(const s8v*)(thp + ks * 32);
  }
  f4v acc_y[8];
#pragma unroll
  for (int i = 0; i < 8; ++i) acc_y[i] = zero;
  float m_run = -1e30f, l_run = 0.f;
  char* pw = (char*)&plds[w][0];
  const int byte0 = tid * 16;
  s8v rp[4], rg[4];

  auto load_t = [&](int m0) {
    const char* sp = phsrc + (long)m0 * 256;
    const char* sg = gsrc + (long)m0 * 2;
#pragma unroll
    for (int j = 0; j < 4; ++j) {
      int byte = j * 4096 + byte0;
      rp[j] = *(const s8v*)(sp + byte);
      rg[j] = *(const s8v*)(sg + (long)(byte >> 7) * 8192 + (byte & 127));
    }
  };
  auto store_t = [&](int bufi) {
    char* dp = (char*)ph2[bufi];
    char* dg = (char*)g2[bufi];
#pragma unroll
    for (int j = 0; j < 4; ++j) {
      int byte = j * 4096 + byte0;
      int row = byte >> 8, kb = byte & 255;
      *(s8v*)(dp + row * 256 + (kb ^ ((row & 7) << 4))) = rp[j];
      int rowg = byte >> 7, kbg = byte & 127;
      *(s8v*)(dg + SW(rowg, kbg)) = rg[j];
    }
  };

  load_t(0);
  store_t(0);
  __syncthreads();

  for (int mt = 0; mt < 64; ++mt) {
    const int cur = mt & 1;
    load_t(((mt + 1) & 63) * 64);
    const char* phb = (const char*)ph2[cur];
    const char* gb = (const char*)g2[cur];

    // S^T[m][q] = K . Q^T : lane owns q = lr, m = ct*16 + lg*4 + r
    f4v s_[4];
#pragma unroll
    for (int ct = 0; ct < 4; ++ct) s_[ct] = zero;
    __builtin_amdgcn_s_setprio(1);
#pragma unroll
    for (int ks = 0; ks < 4; ++ks) {
      const int kb = ks * 64 + lg * 16;
#pragma unroll
      for (int ct = 0; ct < 4; ++ct) {
        int row = ct * 16 + lr;
        s8v kf = *(const s8v*)(phb + row * 256 + (kb ^ ((row & 7) << 4)));
        s_[ct] = __builtin_amdgcn_mfma_f32_16x16x32_bf16(kf, a_th[ks], s_[ct], 0, 0, 0);
      }
    }
    __builtin_amdgcn_s_setprio(0);

    // row max over 16 in-register + 2 shfl (lanes lr, lr+16, lr+32, lr+48 share q)
    float m0 = fmaxf(fmaxf(s_[0][0], s_[0][1]), fmaxf(s_[0][2], s_[0][3]));
    float m1 = fmaxf(fmaxf(s_[1][0], s_[1][1]), fmaxf(s_[1][2], s_[1][3]));
    float m2 = fmaxf(fmaxf(s_[2][0], s_[2][1]), fmaxf(s_[2][2], s_[2][3]));
    float m3 = fmaxf(fmaxf(s_[3][0], s_[3][1]), fmaxf(s_[3][2], s_[3][3]));
    float mx = fmaxf(fmaxf(m0, m1), fmaxf(m2, m3));
    mx = fmaxf(mx, __shfl_xor(mx, 16, 64));
    mx = fmaxf(mx, __shfl_xor(mx, 32, 64));

    // defer-max (T13): raw-score threshold 60 -> p <= e^5.3 ~ 200, bf16-safe
    if (__any(mx > m_run + 60.0f)) {
      float mn = fmaxf(m_run, mx);
      float corr = __builtin_amdgcn_exp2f((m_run - mn) * C1);
      m_run = mn;
      l_run *= corr;
      float cb0 = __shfl(corr, lg * 4 + 0, 64);
      float cb1 = __shfl(corr, lg * 4 + 1, 64);
      float cb2 = __shfl(corr, lg * 4 + 2, 64);
      float cb3 = __shfl(corr, lg * 4 + 3, 64);
#pragma unroll
      for (int dt = 0; dt < 8; ++dt) {
        acc_y[dt][0] *= cb0; acc_y[dt][1] *= cb1;
        acc_y[dt][2] *= cb2; acc_y[dt][3] *= cb3;
      }
    }

    // P = exp2((s-m)*C1), packed to bf16 pairs via v_perm, summed in-register
    float sum = 0.f;
    unsigned pk[8];
#pragma unroll
    for (int ct = 0; ct < 4; ++ct) {
      float p0 = __builtin_amdgcn_exp2f((s_[ct][0] - m_run) * C1);
      float p1 = __builtin_amdgcn_exp2f((s_[ct][1] - m_run) * C1);
      float p2 = __builtin_amdgcn_exp2f((s_[ct][2] - m_run) * C1);
      float p3 = __builtin_amdgcn_exp2f((s_[ct][3] - m_run) * C1);
      sum += (p0 + p1) + (p2 + p3);
      pk[ct * 2] = __builtin_amdgcn_perm(__builtin_bit_cast(unsigned, p1),
                                         __builtin_bit_cast(unsigned, p0), 0x07060302u);
      pk[ct * 2 + 1] = __builtin_amdgcn_perm(__builtin_bit_cast(unsigned, p3),
                                             __builtin_bit_cast(unsigned, p2), 0x07060302u);
    }
    sum += __shfl_xor(sum, 16, 64);
    sum += __shfl_xor(sum, 32, 64);
    l_run += sum;

    // write P row q=lr (4x ds_write_b64, bandwidth-minimal)
#pragma unroll
    for (int ct = 0; ct < 4; ++ct) {
      uint2 v; v.x = pk[ct * 2]; v.y = pk[ct * 2 + 1];
      *(uint2*)(pw + lr * 128 + ((ct * 32 + lg * 8) ^ ((lr & 7) << 4))) = v;
    }

    // PV: y[16 q][128 dd] += P[16 q][64 m] . g[64 m][128 dd]
#pragma unroll
    for (int ks2 = 0; ks2 < 2; ++ks2) {
      const int kb = ks2 * 64 + lg * 16;
      s8v ap = *(const s8v*)(pw + lr * 128 + (kb ^ ((lr & 7) << 4)));
      __builtin_amdgcn_s_setprio(1);
#pragma unroll
      for (int dt = 0; dt < 8; ++dt) {
        int row = lr + 16 * dt;
        s8v bg = *(const s8v*)(gb + SW(row, kb));
        acc_y[dt] = __builtin_amdgcn_mfma_f32_16x16x32_bf16(ap, bg, acc_y[dt], 0, 0, 0);
      }
      __builtin_amdgcn_s_setprio(0);
    }

    store_t(cur ^ 1);
    __syncthreads();
  }

  // epilogue: acc row q' = lg*4+r needs l_run from lane q'
  float inv = 1.0f / l_run;
  float i0 = __shfl(inv, lg * 4 + 0, 64);
  float i1 = __shfl(inv, lg * 4 + 1, 64);
  float i2 = __shfl(inv, lg * 4 + 2, 64);
  float i3 = __shfl(inv, lg * 4 + 3, 64);
  float iv[4] = {i0, i1, i2, i3};
#pragma unroll
  for (int r = 0; r < 4; ++r) {
    long n = (long)qb * 64 + w * 16 + lg * 4 + r;
    us* dst = yt + ((long)b * 4096 + n) * 256 + head * 128 + lr;
#pragma unroll
    for (int dt = 0; dt < 8; ++dt) dst[dt * 16] = f2b(acc_y[dt][r] * iv[r]);
  }
}

extern "C" void kernel_launch(void* const* d_in, const int* in_sizes, int n_in,
                              void* d_out, int out_size, void* d_ws, size_t ws_size,
                              hipStream_t stream) {
  (void)in_sizes; (void)n_in; (void)out_size;
  const float* x       = (const float*)d_in[0];
  const float* oa      = (const float*)d_in[1];
  const float* mlp_w   = (const float*)d_in[2];
  const float* mlp_b   = (const float*)d_in[3];
  const float* g_w     = (const float*)d_in[4];
  const float* g_b     = (const float*)d_in[5];
  const float* theta_w = (const float*)d_in[6];
  const float* theta_b = (const float*)d_in[7];
  const float* phi_w   = (const float*)d_in[8];
  const float* phi_b   = (const float*)d_in[9];
  const float* out_w   = (const float*)d_in[10];
  const float* out_b   = (const float*)d_in[11];
  float* out = (float*)d_out;
  char* ws = (char*)d_ws;

  us* xf_t   = (us*)(ws + 0L);          // [4096][2048] bf16
  us* oat    = (us*)(ws + 16777216L);   // [4096][2048] bf16
  us* xt     = (us*)(ws + 33554432L);   // [4096][2048] bf16 (x^T, MLP epilogue)
  us* g_ws   = (us*)(ws + 33554432L);   // [4][256][4096] (aliases xt)
  us* th_ws  = (us*)(ws + 41943040L);   // [8][4096][128]
  us* xc     = (us*)(ws + 50331648L);   // [2048][4096] (x cast, MLP B)
  us* ph_ws  = (us*)(ws + 50331648L);   // [8][4096][128] (aliases xc)
  us* yt     = (us*)(ws + 58720256L);   // [4][4096][256]
  us* g_wb   = (us*)(ws + 67108864L);
  us* th_wb  = (us*)(ws + 67371008L);
  us* ph_wb  = (us*)(ws + 67633152L);
  us* out_wb = (us*)(ws + 67895296L);
  us* mlp_wb = (us*)(ws + 68157440L);   // [4096][4096] bf16 (needs big ws)
  const bool big = ws_size >= 101711872ULL;

  wcast4<<<dim3(32, 4), dim3(256), 0, stream>>>(g_w, g_wb, theta_w, th_wb,
                                                phi_w, ph_wb, out_w, out_wb);
  castk<<<dim3(1024), dim3(256), 0, stream>>>(x, xc, 2097152);
  tcast<<<dim3(64, 32), dim3(256), 0, stream>>>(x, xt, 2048, 4096);
  tcast<<<dim3(64, 32), dim3(256), 0, stream>>>(oa, oat, 2048, 4096);

  // MLP remix: xf_t[m][r] = sum_n mlp_w[m][n]*x[r][n] + x[r][m] + mlp_b[m]
  if (big) {
    castk<<<dim3(1024), dim3(256), 0, stream>>>(mlp_w, mlp_wb, 4194304);
    gemm_nt<0, 0, 0, 1><<<dim3(32, 16, 1), dim3(256), 0, stream>>>(
        mlp_wb, xc, 4096, 4096, 4096, 0, 0, mlp_b, xt, nullptr, xf_t, nullptr);
  } else {
    gemm_nt<0, 1, 0, 1><<<dim3(32, 16, 1), dim3(256), 0, stream>>>(
        mlp_w, xc, 4096, 4096, 4096, 0, 0, mlp_b, xt, nullptr, xf_t, nullptr);
  }

  // theta / phi / g 1x1 convs
  gemm_nt<1, 0, 0, 0><<<dim3(32, 2, 4), dim3(256), 0, stream>>>(
      oat, th_wb, 2048, 512, 512, 512, 0, theta_b, nullptr, nullptr, th_ws, nullptr);
  gemm_nt<1, 0, 0, 0><<<dim3(32, 2, 4), dim3(256), 0, stream>>>(
      xf_t, ph_wb, 2048, 512, 512, 512, 0, phi_b, nullptr, nullptr, ph_ws, nullptr);
  gemm_nt<2, 0, 0, 0><<<dim3(2, 32, 4), dim3(256), 0, stream>>>(
      g_wb, xf_t, 512, 2048, 512, 0, 512, g_b, nullptr, nullptr, g_ws, nullptr);

  // fused softmax attention
  attn_k<<<dim3(64, 8), dim3(256), 0, stream>>>(th_ws, ph_ws, g_ws, yt);

  // final conv + residual
  gemm_nt<3, 0, 0, 0><<<dim3(4, 32, 4), dim3(256), 0, stream>>>(
      out_wb, yt, 256, 256, 256, 0, 1048576L, out_b, nullptr, oa, nullptr, out);
}

// Round 4
// 306.896 us; speedup vs baseline: 1.7909x; 1.0168x over previous
//
#include <hip/hip_runtime.h>

typedef unsigned short us;
typedef us s8v __attribute__((ext_vector_type(8)));   // 8 bf16 (4 VGPRs)
typedef us s4v __attribute__((ext_vector_type(4)));
typedef float f4v __attribute__((ext_vector_type(4)));
typedef __bf16 b2v __attribute__((ext_vector_type(2)));

// HW bf16 convert (RNE via v_cvt_pk_bf16_f32; compiler packs adjacent pairs)
static __device__ __forceinline__ us f2b(float f) {
  return __builtin_bit_cast(us, (__bf16)f);
}
static __device__ __forceinline__ unsigned f2b2(float lo, float hi) {
  b2v v = {(__bf16)lo, (__bf16)hi};
  return __builtin_bit_cast(unsigned, v);
}
static __device__ __forceinline__ float b2f(us s) {
  unsigned u = ((unsigned)s) << 16;
  return __builtin_bit_cast(float, u);
}

#define GLDS(src, dst)                                                        \
  __builtin_amdgcn_global_load_lds(                                           \
      (const __attribute__((address_space(1))) unsigned int*)(src),           \
      (__attribute__((address_space(3))) unsigned int*)(dst), 16, 0, 0)

// ---------------- flat f32 -> bf16 cast ----------------
__global__ __launch_bounds__(256) void castk(const float* __restrict__ in,
                                             us* __restrict__ out, int n4) {
  int i = blockIdx.x * 256 + threadIdx.x;
  int stride = gridDim.x * 256;
  for (; i < n4; i += stride) {
    float4 v = ((const float4*)in)[i];
    s4v s = {f2b(v.x), f2b(v.y), f2b(v.z), f2b(v.w)};
    ((s4v*)out)[i] = s;
  }
}

// 4 weight casts in one launch (each 131072 f32 -> bf16)
__global__ __launch_bounds__(256) void wcast4(const float* __restrict__ s0, us* __restrict__ o0,
                                              const float* __restrict__ s1, us* __restrict__ o1,
                                              const float* __restrict__ s2, us* __restrict__ o2,
                                              const float* __restrict__ s3, us* __restrict__ o3) {
  const float* s; us* o;
  int y = blockIdx.y;
  if (y == 0) { s = s0; o = o0; }
  else if (y == 1) { s = s1; o = o1; }
  else if (y == 2) { s = s2; o = o2; }
  else { s = s3; o = o3; }
  int i = blockIdx.x * 256 + threadIdx.x;
  for (; i < 32768; i += 8192) {
    float4 v = ((const float4*)s)[i];
    s4v r = {f2b(v.x), f2b(v.y), f2b(v.z), f2b(v.w)};
    ((s4v*)o)[i] = r;
  }
}

// ---------------- transpose-cast: f32 [R][C] -> bf16 [C][R] ----------------
__global__ __launch_bounds__(256) void tcast(const float* __restrict__ in,
                                             us* __restrict__ out, int R, int C) {
  __shared__ float t[64][65];
  const int tid = threadIdx.x;
  const long r0 = (long)blockIdx.y * 64, c0 = (long)blockIdx.x * 64;
#pragma unroll
  for (int j = 0; j < 4; ++j) {
    int idx = j * 256 + tid;
    int row = idx >> 4, c4 = (idx & 15) * 4;
    float4 v = *(const float4*)(in + (r0 + row) * C + c0 + c4);
    t[row][c4] = v.x; t[row][c4 + 1] = v.y; t[row][c4 + 2] = v.z; t[row][c4 + 3] = v.w;
  }
  __syncthreads();
#pragma unroll
  for (int j = 0; j < 4; ++j) {
    int idx = j * 256 + tid;
    int orow = idx >> 4, r4 = (idx & 15) * 4;
    s4v s = {f2b(t[r4][orow]), f2b(t[r4 + 1][orow]), f2b(t[r4 + 2][orow]), f2b(t[r4 + 3][orow])};
    *(s4v*)(out + (c0 + orow) * R + r0 + r4) = s;
  }
}

// byte-offset into a [rows][128 B] LDS tile, XOR-swizzled (T2)
#define SW(row, kb) ((row) * 128 + ((kb) ^ (((row) & 7) << 4)))

// ---------------- generic NT bf16 MFMA GEMM, 128x128 tile, BK=64 ----------------
template <int EPI, int AF32, int BF32, int SWZ>
__global__ __launch_bounds__(256) void gemm_nt(
    const void* __restrict__ Av, const void* __restrict__ Bv,
    int lda, int ldb, int K, long aZ, long bZ,
    const float* __restrict__ bias,
    const us* __restrict__ addb16,
    const float* __restrict__ addf32,
    us* __restrict__ outb16,
    float* __restrict__ outf32) {
  __shared__ __align__(16) us lA[128 * 64];
  __shared__ __align__(16) us lB[128 * 64];
  const int tid = threadIdx.x, l = tid & 63;
  const int lr = l & 15, lg = l >> 4;
  const int w = tid >> 6, wr = w >> 1, wc = w & 1;
  int bm, bn;
  if constexpr (SWZ) {   // XCD-contiguous remap (requires nwg % 8 == 0)
    int flat = blockIdx.y * gridDim.x + blockIdx.x;
    int re = (flat & 7) * ((gridDim.x * gridDim.y) >> 3) + (flat >> 3);
    bm = re % gridDim.x; bn = re / gridDim.x;
  } else { bm = blockIdx.x; bn = blockIdx.y; }
  const int z = blockIdx.z;
  const f4v zero = {0.f, 0.f, 0.f, 0.f};
  f4v acc[4][4];
#pragma unroll
  for (int i = 0; i < 4; ++i)
#pragma unroll
    for (int j = 0; j < 4; ++j) acc[i][j] = zero;
  char* lab = (char*)lA;
  char* lbb = (char*)lB;

  for (int k0 = 0; k0 < K; k0 += 64) {
#pragma unroll
    for (int j = 0; j < 4; ++j) {
      int byte = j * 4096 + tid * 16;
      int row = byte >> 7, kb = byte & 127;
      if constexpr (AF32) {
        const float* af = (const float*)Av + (long)z * aZ + (long)(bm * 128 + row) * lda + k0 + (kb >> 1);
        float4 v0 = *(const float4*)af, v1 = *(const float4*)(af + 4);
        s8v va = {f2b(v0.x), f2b(v0.y), f2b(v0.z), f2b(v0.w), f2b(v1.x), f2b(v1.y), f2b(v1.z), f2b(v1.w)};
        *(s8v*)(lab + SW(row, kb)) = va;
      } else {
        s8v va = *(const s8v*)((const char*)Av + ((long)z * aZ + (long)(bm * 128 + row) * lda + k0) * 2 + kb);
        *(s8v*)(lab + SW(row, kb)) = va;
      }
      if constexpr (BF32) {
        const float* bf_ = (const float*)Bv + (long)z * bZ + (long)(bn * 128 + row) * ldb + k0 + (kb >> 1);
        float4 v0 = *(const float4*)bf_, v1 = *(const float4*)(bf_ + 4);
        s8v vb = {f2b(v0.x), f2b(v0.y), f2b(v0.z), f2b(v0.w), f2b(v1.x), f2b(v1.y), f2b(v1.z), f2b(v1.w)};
        *(s8v*)(lbb + SW(row, kb)) = vb;
      } else {
        s8v vb = *(const s8v*)((const char*)Bv + ((long)z * bZ + (long)(bn * 128 + row) * ldb + k0) * 2 + kb);
        *(s8v*)(lbb + SW(row, kb)) = vb;
      }
    }
    __syncthreads();
#pragma unroll
    for (int ks = 0; ks < 2; ++ks) {
      s8v af[4], bf[4];
      const int kb = ks * 64 + lg * 16;
#pragma unroll
      for (int mi = 0; mi < 4; ++mi) {
        int row = wr * 64 + mi * 16 + lr;
        af[mi] = *(const s8v*)(lab + SW(row, kb));
      }
#pragma unroll
      for (int ni = 0; ni < 4; ++ni) {
        int row = wc * 64 + ni * 16 + lr;
        bf[ni] = *(const s8v*)(lbb + SW(row, kb));
      }
#pragma unroll
      for (int mi = 0; mi < 4; ++mi)
#pragma unroll
        for (int ni = 0; ni < 4; ++ni)
          acc[mi][ni] = __builtin_amdgcn_mfma_f32_16x16x32_bf16(af[mi], bf[ni], acc[mi][ni], 0, 0, 0);
    }
    __syncthreads();
  }

#pragma unroll
  for (int mi = 0; mi < 4; ++mi) {
#pragma unroll
    for (int ni = 0; ni < 4; ++ni) {
#pragma unroll
      for (int r = 0; r < 4; ++r) {
        int row = bm * 128 + wr * 64 + mi * 16 + lg * 4 + r;
        int col = bn * 128 + wc * 64 + ni * 16 + lr;
        float v = acc[mi][ni][r];
        if constexpr (EPI == 0) {
          long idx = (long)row * 2048 + col;
          outb16[idx] = f2b(v + b2f(addb16[idx]) + bias[row]);
        } else if constexpr (EPI == 1) {
          long idx = ((long)(z * 2 + (col >> 7)) * 4096 + row) * 128 + (col & 127);
          outb16[idx] = f2b(v + bias[col]);
        } else if constexpr (EPI == 2) {
          long idx = ((long)(z * 256 + row)) * 4096 + col;
          outb16[idx] = f2b(v + bias[row]);
        } else {
          long idx = ((long)(z * 512 + row)) * 4096 + col;
          outf32[idx] = v + bias[row] + addf32[idx];
        }
      }
    }
  }
}

// ---------------- fused flash attention ------------------------------------------
// swapped QK^T (in-register softmax) + global_load_lds staging with pre-swizzled
// source addresses (LDS stays linear-dest; readers apply the same XOR involution).
// th  [8][4096][128]  (Q)   pht [8][4096][128] (K)
// g   [4][256][4096]  (V, [dd][m])   yt [4][4096][256]
__global__ __launch_bounds__(256) void attn_k(const us* __restrict__ th,
                                              const us* __restrict__ pht,
                                              const us* __restrict__ g,
                                              us* __restrict__ yt) {
  __shared__ __align__(16) us ph2[2][64 * 128];   // K tiles [m 64][dd 128]
  __shared__ __align__(16) us g2[2][128 * 64];    // V tiles [dd 128][m 64]
  __shared__ __align__(16) us plds[4][1024];      // per-wave P [16 q][64 m]
  const int tid = threadIdx.x, l = tid & 63, w = tid >> 6;
  const int lr = l & 15, lg = l >> 4;
  const int flat = blockIdx.y * 64 + blockIdx.x;
  const int bh = flat & 7, qb = flat >> 3;        // XCD c <- bh c : K/V L2-resident
  const int b = bh >> 1, head = bh & 1;
  const float C1 = 0.12751802f;                   // (1/sqrt(128)) * log2(e)
  const f4v zero = {0.f, 0.f, 0.f, 0.f};

  const char* phsrc = (const char*)(pht + (long)bh * 4096 * 128);
  const char* gsrc = (const char*)(g + (long)(b * 256 + head * 128) * 4096);

  // per-lane pre-swizzled source offsets (rule 21: linear LDS dest + inv-swz src)
  int koff[4], voff[4];
#pragma unroll
  for (int j = 0; j < 4; ++j) {
    int d = j * 4096 + tid * 16;
    koff[j] = d ^ (((d >> 8) & 7) << 4);
    int rowg = d >> 7, kbg = d & 127;
    voff[j] = rowg * 8192 + (kbg ^ ((rowg & 7) << 4));
  }

  s8v a_th[4];   // Q rows w*16+lr, k = ks*32 + lg*8 .. +7  (B-operand)
  {
    const us* thp = th + ((long)bh * 4096 + qb * 64 + w * 16 + lr) * 128 + lg * 8;
#pragma unroll
    for (int ks = 0; ks < 4; ++ks) a_th[ks] = *(const s8v*)(thp + ks * 32);
  }
  f4v acc_y[8];
#pragma unroll
  for (int i = 0; i < 8; ++i) acc_y[i] = zero;
  float m_run = -1e30f, l_run = 0.f;
  char* pw = (char*)&plds[w][0];

  auto stage = [&](int bufi, int mt2) {
    char* dk = (char*)ph2[bufi] + w * 1024;       // wave-uniform dest base
    char* dv = (char*)g2[bufi] + w * 1024;
    const char* sk = phsrc + (long)mt2 * 16384;
    const char* sv = gsrc + (long)mt2 * 128;
#pragma unroll
    for (int j = 0; j < 4; ++j) {
      GLDS(sk + koff[j], dk + j * 4096);
      GLDS(sv + voff[j], dv + j * 4096);
    }
  };

  stage(0, 0);
  __syncthreads();

  for (int mt = 0; mt < 64; ++mt) {
    const int cur = mt & 1;
    stage(cur ^ 1, (mt + 1) & 63);   // async; lands before end-of-iter barrier
    const char* phb = (const char*)ph2[cur];
    const char* gb = (const char*)g2[cur];

    // S^T[m][q] = K . Q^T : lane owns q = lr, m = ct*16 + lg*4 + r
    f4v s_[4];
#pragma unroll
    for (int ct = 0; ct < 4; ++ct) s_[ct] = zero;
    __builtin_amdgcn_s_setprio(1);
#pragma unroll
    for (int ks = 0; ks < 4; ++ks) {
      const int kb = ks * 64 + lg * 16;
#pragma unroll
      for (int ct = 0; ct < 4; ++ct) {
        int row = ct * 16 + lr;
        s8v kf = *(const s8v*)(phb + row * 256 + (kb ^ ((row & 7) << 4)));
        s_[ct] = __builtin_amdgcn_mfma_f32_16x16x32_bf16(kf, a_th[ks], s_[ct], 0, 0, 0);
      }
    }
    __builtin_amdgcn_s_setprio(0);

    // row max: 15 in-register fmax + 2 shfl
    float m0 = fmaxf(fmaxf(s_[0][0], s_[0][1]), fmaxf(s_[0][2], s_[0][3]));
    float m1 = fmaxf(fmaxf(s_[1][0], s_[1][1]), fmaxf(s_[1][2], s_[1][3]));
    float m2 = fmaxf(fmaxf(s_[2][0], s_[2][1]), fmaxf(s_[2][2], s_[2][3]));
    float m3 = fmaxf(fmaxf(s_[3][0], s_[3][1]), fmaxf(s_[3][2], s_[3][3]));
    float mx = fmaxf(fmaxf(m0, m1), fmaxf(m2, m3));
    mx = fmaxf(mx, __shfl_xor(mx, 16, 64));
    mx = fmaxf(mx, __shfl_xor(mx, 32, 64));

    // defer-max (T13): raw-score threshold 60 -> p <= e^5.3 ~ 200, bf16-safe
    if (__any(mx > m_run + 60.0f)) {
      float mn = fmaxf(m_run, mx);
      float corr = __builtin_amdgcn_exp2f((m_run - mn) * C1);
      m_run = mn;
      l_run *= corr;
      float cb0 = __shfl(corr, lg * 4 + 0, 64);
      float cb1 = __shfl(corr, lg * 4 + 1, 64);
      float cb2 = __shfl(corr, lg * 4 + 2, 64);
      float cb3 = __shfl(corr, lg * 4 + 3, 64);
#pragma unroll
      for (int dt = 0; dt < 8; ++dt) {
        acc_y[dt][0] *= cb0; acc_y[dt][1] *= cb1;
        acc_y[dt][2] *= cb2; acc_y[dt][3] *= cb3;
      }
    }

    // P = exp2(s*C1 - m*C1) (1 fma + 1 exp each), cvt_pk packed, summed in-register
    const float nmsc = -m_run * C1;
    float sum = 0.f;
    unsigned pk[8];
#pragma unroll
    for (int ct = 0; ct < 4; ++ct) {
      float p0 = __builtin_amdgcn_exp2f(__builtin_fmaf(s_[ct][0], C1, nmsc));
      float p1 = __builtin_amdgcn_exp2f(__builtin_fmaf(s_[ct][1], C1, nmsc));
      float p2 = __builtin_amdgcn_exp2f(__builtin_fmaf(s_[ct][2], C1, nmsc));
      float p3 = __builtin_amdgcn_exp2f(__builtin_fmaf(s_[ct][3], C1, nmsc));
      sum += (p0 + p1) + (p2 + p3);
      pk[ct * 2] = f2b2(p0, p1);
      pk[ct * 2 + 1] = f2b2(p2, p3);
    }
    sum += __shfl_xor(sum, 16, 64);
    sum += __shfl_xor(sum, 32, 64);
    l_run += sum;

    // write P row q=lr (4x ds_write_b64)
#pragma unroll
    for (int ct = 0; ct < 4; ++ct) {
      uint2 v; v.x = pk[ct * 2]; v.y = pk[ct * 2 + 1];
      *(uint2*)(pw + lr * 128 + ((ct * 32 + lg * 8) ^ ((lr & 7) << 4))) = v;
    }

    // PV: y[16 q][128 dd] += P[16 q][64 m] . g[64 m][128 dd]
#pragma unroll
    for (int ks2 = 0; ks2 < 2; ++ks2) {
      const int kb = ks2 * 64 + lg * 16;
      s8v ap = *(const s8v*)(pw + lr * 128 + (kb ^ ((lr & 7) << 4)));
      __builtin_amdgcn_s_setprio(1);
#pragma unroll
      for (int dt = 0; dt < 8; ++dt) {
        int row = lr + 16 * dt;
        s8v bg = *(const s8v*)(gb + SW(row, kb));
        acc_y[dt] = __builtin_amdgcn_mfma_f32_16x16x32_bf16(ap, bg, acc_y[dt], 0, 0, 0);
      }
      __builtin_amdgcn_s_setprio(0);
    }

    __syncthreads();   // drains staging vmcnt + publishes buf cur^1
  }

  // epilogue: acc row q' = lg*4+r needs l_run from lane q'
  float inv = 1.0f / l_run;
  float i0 = __shfl(inv, lg * 4 + 0, 64);
  float i1 = __shfl(inv, lg * 4 + 1, 64);
  float i2 = __shfl(inv, lg * 4 + 2, 64);
  float i3 = __shfl(inv, lg * 4 + 3, 64);
  float iv[4] = {i0, i1, i2, i3};
#pragma unroll
  for (int r = 0; r < 4; ++r) {
    long n = (long)qb * 64 + w * 16 + lg * 4 + r;
    us* dst = yt + ((long)b * 4096 + n) * 256 + head * 128 + lr;
#pragma unroll
    for (int dt = 0; dt < 8; ++dt) dst[dt * 16] = f2b(acc_y[dt][r] * iv[r]);
  }
}

extern "C" void kernel_launch(void* const* d_in, const int* in_sizes, int n_in,
                              void* d_out, int out_size, void* d_ws, size_t ws_size,
                              hipStream_t stream) {
  (void)in_sizes; (void)n_in; (void)out_size;
  const float* x       = (const float*)d_in[0];
  const float* oa      = (const float*)d_in[1];
  const float* mlp_w   = (const float*)d_in[2];
  const float* mlp_b   = (const float*)d_in[3];
  const float* g_w     = (const float*)d_in[4];
  const float* g_b     = (const float*)d_in[5];
  const float* theta_w = (const float*)d_in[6];
  const float* theta_b = (const float*)d_in[7];
  const float* phi_w   = (const float*)d_in[8];
  const float* phi_b   = (const float*)d_in[9];
  const float* out_w   = (const float*)d_in[10];
  const float* out_b   = (const float*)d_in[11];
  float* out = (float*)d_out;
  char* ws = (char*)d_ws;

  us* xf_t   = (us*)(ws + 0L);          // [4096][2048] bf16
  us* oat    = (us*)(ws + 16777216L);   // [4096][2048] bf16
  us* xt     = (us*)(ws + 33554432L);   // [4096][2048] bf16 (x^T, MLP epilogue)
  us* g_ws   = (us*)(ws + 33554432L);   // [4][256][4096] (aliases xt)
  us* th_ws  = (us*)(ws + 41943040L);   // [8][4096][128]
  us* xc     = (us*)(ws + 50331648L);   // [2048][4096] (x cast, MLP B)
  us* ph_ws  = (us*)(ws + 50331648L);   // [8][4096][128] (aliases xc)
  us* yt     = (us*)(ws + 58720256L);   // [4][4096][256]
  us* g_wb   = (us*)(ws + 67108864L);
  us* th_wb  = (us*)(ws + 67371008L);
  us* ph_wb  = (us*)(ws + 67633152L);
  us* out_wb = (us*)(ws + 67895296L);
  us* mlp_wb = (us*)(ws + 68157440L);   // [4096][4096] bf16 (needs big ws)
  const bool big = ws_size >= 101711872ULL;

  wcast4<<<dim3(32, 4), dim3(256), 0, stream>>>(g_w, g_wb, theta_w, th_wb,
                                                phi_w, ph_wb, out_w, out_wb);
  castk<<<dim3(1024), dim3(256), 0, stream>>>(x, xc, 2097152);
  tcast<<<dim3(64, 32), dim3(256), 0, stream>>>(x, xt, 2048, 4096);
  tcast<<<dim3(64, 32), dim3(256), 0, stream>>>(oa, oat, 2048, 4096);

  // MLP remix: xf_t[m][r] = sum_n mlp_w[m][n]*x[r][n] + x[r][m] + mlp_b[m]
  if (big) {
    castk<<<dim3(1024), dim3(256), 0, stream>>>(mlp_w, mlp_wb, 4194304);
    gemm_nt<0, 0, 0, 1><<<dim3(32, 16, 1), dim3(256), 0, stream>>>(
        mlp_wb, xc, 4096, 4096, 4096, 0, 0, mlp_b, xt, nullptr, xf_t, nullptr);
  } else {
    gemm_nt<0, 1, 0, 1><<<dim3(32, 16, 1), dim3(256), 0, stream>>>(
        mlp_w, xc, 4096, 4096, 4096, 0, 0, mlp_b, xt, nullptr, xf_t, nullptr);
  }

  // theta / phi / g 1x1 convs
  gemm_nt<1, 0, 0, 0><<<dim3(32, 2, 4), dim3(256), 0, stream>>>(
      oat, th_wb, 2048, 512, 512, 512, 0, theta_b, nullptr, nullptr, th_ws, nullptr);
  gemm_nt<1, 0, 0, 0><<<dim3(32, 2, 4), dim3(256), 0, stream>>>(
      xf_t, ph_wb, 2048, 512, 512, 512, 0, phi_b, nullptr, nullptr, ph_ws, nullptr);
  gemm_nt<2, 0, 0, 0><<<dim3(2, 32, 4), dim3(256), 0, stream>>>(
      g_wb, xf_t, 512, 2048, 512, 0, 512, g_b, nullptr, nullptr, g_ws, nullptr);

  // fused softmax attention
  attn_k<<<dim3(64, 8), dim3(256), 0, stream>>>(th_ws, ph_ws, g_ws, yt);

  // final conv + residual
  gemm_nt<3, 0, 0, 0><<<dim3(4, 32, 4), dim3(256), 0, stream>>>(
      out_wb, yt, 256, 256, 256, 0, 1048576L, out_b, nullptr, oa, nullptr, out);
}

// Round 5
// 280.287 us; speedup vs baseline: 1.9610x; 1.0949x over previous
//
#include <hip/hip_runtime.h>

typedef unsigned short us;
typedef us s8v __attribute__((ext_vector_type(8)));   // 8 bf16 (4 VGPRs)
typedef us s4v __attribute__((ext_vector_type(4)));
typedef float f4v __attribute__((ext_vector_type(4)));
typedef float f16v __attribute__((ext_vector_type(16)));
typedef __bf16 b2v __attribute__((ext_vector_type(2)));

// HW bf16 convert (RNE via v_cvt_pk_bf16_f32; compiler packs adjacent pairs)
static __device__ __forceinline__ us f2b(float f) {
  return __builtin_bit_cast(us, (__bf16)f);
}
static __device__ __forceinline__ unsigned f2b2(float lo, float hi) {
  b2v v = {(__bf16)lo, (__bf16)hi};
  return __builtin_bit_cast(unsigned, v);
}
static __device__ __forceinline__ float b2f(us s) {
  unsigned u = ((unsigned)s) << 16;
  return __builtin_bit_cast(float, u);
}

#define GLDS(src, dst)                                                        \
  __builtin_amdgcn_global_load_lds(                                           \
      (const __attribute__((address_space(1))) unsigned int*)(src),           \
      (__attribute__((address_space(3))) unsigned int*)(dst), 16, 0, 0)

// ---------------- flat f32 -> bf16 cast ----------------
__global__ __launch_bounds__(256) void castk(const float* __restrict__ in,
                                             us* __restrict__ out, int n4) {
  int i = blockIdx.x * 256 + threadIdx.x;
  int stride = gridDim.x * 256;
  for (; i < n4; i += stride) {
    float4 v = ((const float4*)in)[i];
    s4v s = {f2b(v.x), f2b(v.y), f2b(v.z), f2b(v.w)};
    ((s4v*)out)[i] = s;
  }
}

// 4 weight casts in one launch (each 131072 f32 -> bf16)
__global__ __launch_bounds__(256) void wcast4(const float* __restrict__ s0, us* __restrict__ o0,
                                              const float* __restrict__ s1, us* __restrict__ o1,
                                              const float* __restrict__ s2, us* __restrict__ o2,
                                              const float* __restrict__ s3, us* __restrict__ o3) {
  const float* s; us* o;
  int y = blockIdx.y;
  if (y == 0) { s = s0; o = o0; }
  else if (y == 1) { s = s1; o = o1; }
  else if (y == 2) { s = s2; o = o2; }
  else { s = s3; o = o3; }
  int i = blockIdx.x * 256 + threadIdx.x;
  for (; i < 32768; i += 8192) {
    float4 v = ((const float4*)s)[i];
    s4v r = {f2b(v.x), f2b(v.y), f2b(v.z), f2b(v.w)};
    ((s4v*)o)[i] = r;
  }
}

// ---------------- transpose-cast: f32 [R][C] -> bf16 [C][R] ----------------
__global__ __launch_bounds__(256) void tcast(const float* __restrict__ in,
                                             us* __restrict__ out, int R, int C) {
  __shared__ float t[64][65];
  const int tid = threadIdx.x;
  const long r0 = (long)blockIdx.y * 64, c0 = (long)blockIdx.x * 64;
#pragma unroll
  for (int j = 0; j < 4; ++j) {
    int idx = j * 256 + tid;
    int row = idx >> 4, c4 = (idx & 15) * 4;
    float4 v = *(const float4*)(in + (r0 + row) * C + c0 + c4);
    t[row][c4] = v.x; t[row][c4 + 1] = v.y; t[row][c4 + 2] = v.z; t[row][c4 + 3] = v.w;
  }
  __syncthreads();
#pragma unroll
  for (int j = 0; j < 4; ++j) {
    int idx = j * 256 + tid;
    int orow = idx >> 4, r4 = (idx & 15) * 4;
    s4v s = {f2b(t[r4][orow]), f2b(t[r4 + 1][orow]), f2b(t[r4 + 2][orow]), f2b(t[r4 + 3][orow])};
    *(s4v*)(out + (c0 + orow) * R + r0 + r4) = s;
  }
}

// byte-offset into a [rows][128 B] LDS tile, XOR-swizzled (T2)
#define SW(row, kb) ((row) * 128 + ((kb) ^ (((row) & 7) << 4)))

// ---------------- generic NT bf16 MFMA GEMM, 128x128 tile, BK=64 ----------------
template <int EPI, int AF32, int BF32, int SWZ>
__global__ __launch_bounds__(256) void gemm_nt(
    const void* __restrict__ Av, const void* __restrict__ Bv,
    int lda, int ldb, int K, long aZ, long bZ,
    const float* __restrict__ bias,
    const us* __restrict__ addb16,
    const float* __restrict__ addf32,
    us* __restrict__ outb16,
    float* __restrict__ outf32) {
  __shared__ __align__(16) us lA[128 * 64];
  __shared__ __align__(16) us lB[128 * 64];
  const int tid = threadIdx.x, l = tid & 63;
  const int lr = l & 15, lg = l >> 4;
  const int w = tid >> 6, wr = w >> 1, wc = w & 1;
  int bm, bn;
  if constexpr (SWZ) {   // XCD-contiguous remap (requires nwg % 8 == 0)
    int flat = blockIdx.y * gridDim.x + blockIdx.x;
    int re = (flat & 7) * ((gridDim.x * gridDim.y) >> 3) + (flat >> 3);
    bm = re % gridDim.x; bn = re / gridDim.x;
  } else { bm = blockIdx.x; bn = blockIdx.y; }
  const int z = blockIdx.z;
  const f4v zero = {0.f, 0.f, 0.f, 0.f};
  f4v acc[4][4];
#pragma unroll
  for (int i = 0; i < 4; ++i)
#pragma unroll
    for (int j = 0; j < 4; ++j) acc[i][j] = zero;
  char* lab = (char*)lA;
  char* lbb = (char*)lB;

  for (int k0 = 0; k0 < K; k0 += 64) {
#pragma unroll
    for (int j = 0; j < 4; ++j) {
      int byte = j * 4096 + tid * 16;
      int row = byte >> 7, kb = byte & 127;
      if constexpr (AF32) {
        const float* af = (const float*)Av + (long)z * aZ + (long)(bm * 128 + row) * lda + k0 + (kb >> 1);
        float4 v0 = *(const float4*)af, v1 = *(const float4*)(af + 4);
        s8v va = {f2b(v0.x), f2b(v0.y), f2b(v0.z), f2b(v0.w), f2b(v1.x), f2b(v1.y), f2b(v1.z), f2b(v1.w)};
        *(s8v*)(lab + SW(row, kb)) = va;
      } else {
        s8v va = *(const s8v*)((const char*)Av + ((long)z * aZ + (long)(bm * 128 + row) * lda + k0) * 2 + kb);
        *(s8v*)(lab + SW(row, kb)) = va;
      }
      if constexpr (BF32) {
        const float* bf_ = (const float*)Bv + (long)z * bZ + (long)(bn * 128 + row) * ldb + k0 + (kb >> 1);
        float4 v0 = *(const float4*)bf_, v1 = *(const float4*)(bf_ + 4);
        s8v vb = {f2b(v0.x), f2b(v0.y), f2b(v0.z), f2b(v0.w), f2b(v1.x), f2b(v1.y), f2b(v1.z), f2b(v1.w)};
        *(s8v*)(lbb + SW(row, kb)) = vb;
      } else {
        s8v vb = *(const s8v*)((const char*)Bv + ((long)z * bZ + (long)(bn * 128 + row) * ldb + k0) * 2 + kb);
        *(s8v*)(lbb + SW(row, kb)) = vb;
      }
    }
    __syncthreads();
#pragma unroll
    for (int ks = 0; ks < 2; ++ks) {
      s8v af[4], bf[4];
      const int kb = ks * 64 + lg * 16;
#pragma unroll
      for (int mi = 0; mi < 4; ++mi) {
        int row = wr * 64 + mi * 16 + lr;
        af[mi] = *(const s8v*)(lab + SW(row, kb));
      }
#pragma unroll
      for (int ni = 0; ni < 4; ++ni) {
        int row = wc * 64 + ni * 16 + lr;
        bf[ni] = *(const s8v*)(lbb + SW(row, kb));
      }
#pragma unroll
      for (int mi = 0; mi < 4; ++mi)
#pragma unroll
        for (int ni = 0; ni < 4; ++ni)
          acc[mi][ni] = __builtin_amdgcn_mfma_f32_16x16x32_bf16(af[mi], bf[ni], acc[mi][ni], 0, 0, 0);
    }
    __syncthreads();
  }

#pragma unroll
  for (int mi = 0; mi < 4; ++mi) {
#pragma unroll
    for (int ni = 0; ni < 4; ++ni) {
#pragma unroll
      for (int r = 0; r < 4; ++r) {
        int row = bm * 128 + wr * 64 + mi * 16 + lg * 4 + r;
        int col = bn * 128 + wc * 64 + ni * 16 + lr;
        float v = acc[mi][ni][r];
        if constexpr (EPI == 0) {
          long idx = (long)row * 2048 + col;
          outb16[idx] = f2b(v + b2f(addb16[idx]) + bias[row]);
        } else if constexpr (EPI == 1) {
          long idx = ((long)(z * 2 + (col >> 7)) * 4096 + row) * 128 + (col & 127);
          outb16[idx] = f2b(v + bias[col]);
        } else if constexpr (EPI == 2) {
          long idx = ((long)(z * 256 + row)) * 4096 + col;
          outb16[idx] = f2b(v + bias[row]);
        } else {
          long idx = ((long)(z * 512 + row)) * 4096 + col;
          outf32[idx] = v + bias[row] + addf32[idx];
        }
      }
    }
  }
}

// ---------------- fused flash attention, 32x32 fragments, P in registers --------
// Each wave owns 32 q-rows; block = 4 waves (128 q); KV split in 2 halves across
// blocks (flash-decoding), partials merged by mergek.
// th  [8][4096][128] (Q)   pht [8][4096][128] (K)   g [4][256][4096] (V [dd][m])
// pY  [8*4096][2][128] bf16 unnormalized partial Y;  pml [8*4096][2] float2 (m,l)
__global__ __launch_bounds__(256, 2) void attn_k(const us* __restrict__ th,
                                                 const us* __restrict__ pht,
                                                 const us* __restrict__ g,
                                                 us* __restrict__ pY,
                                                 float2* __restrict__ pml) {
  __shared__ __align__(16) us ph2[2][64 * 128];   // K tiles [m 64][dd 128] (256B rows)
  __shared__ __align__(16) us g2[2][128 * 64];    // V tiles [dd 128][m 64] (128B rows)
  const int tid = threadIdx.x, l = tid & 63, w = tid >> 6;
  const int l31 = l & 31, h = l >> 5;
  const int swz = (l & 7) << 4;
  const int flat = blockIdx.y * 32 + blockIdx.x;
  const int bh = flat & 7, rest = flat >> 3;
  const int half = rest & 1, qb = rest >> 1;
  const int b = bh >> 1, head = bh & 1;
  const int m00 = half * 2048;
  const float C1 = 0.12751802f;                   // (1/sqrt(128)) * log2(e)
  const f16v zero16 = {0.f};

  const char* phsrc = (const char*)(pht + (long)bh * 4096 * 128);
  const char* gsrc = (const char*)(g + (long)(b * 256 + head * 128) * 4096);

  // pre-swizzled per-lane source offsets (linear LDS dest + inv-swz src)
  int koff[4], voff[4];
#pragma unroll
  for (int j = 0; j < 4; ++j) {
    int d = j * 4096 + tid * 16;
    koff[j] = d ^ (((d >> 8) & 7) << 4);
    int rowg = d >> 7, kbg = d & 127;
    voff[j] = rowg * 8192 + (kbg ^ ((rowg & 7) << 4));
  }

  // Q fragments: lane holds q = qb*128 + w*32 + l31, dd = ks*16 + h*8 .. +7
  s8v qf[8];
  {
    const us* thp = th + ((long)bh * 4096 + qb * 128 + w * 32 + l31) * 128 + h * 8;
#pragma unroll
    for (int ks = 0; ks < 8; ++ks) qf[ks] = *(const s8v*)(thp + ks * 16);
  }

  f16v acc0 = zero16, acc1 = zero16, acc2 = zero16, acc3 = zero16;
  float m_run = -1e30f, l_run = 0.f;

  auto stage = [&](int bufi, int m0) {
    char* dk = (char*)ph2[bufi] + w * 1024;
    char* dv = (char*)g2[bufi] + w * 1024;
    const char* sk = phsrc + (long)m0 * 256;
    const char* sv = gsrc + (long)m0 * 2;
#pragma unroll
    for (int j = 0; j < 4; ++j) {
      GLDS(sk + koff[j], dk + j * 4096);
      GLDS(sv + voff[j], dv + j * 4096);
    }
  };

  stage(0, m00);
  __syncthreads();

  for (int t = 0; t < 32; ++t) {
    const int cur = t & 1;
    stage(cur ^ 1, m00 + ((t + 1) & 31) * 64);
    const char* phb = (const char*)ph2[cur];
    const char* gb = (const char*)g2[cur];

    // S^T[m][q] = K . Q^T : lane q = l31; sA[mt] rows m = mt*32 + (r&3)+8*(r>>2)+4h
    f16v sA[2] = {zero16, zero16};
    __builtin_amdgcn_s_setprio(1);
#pragma unroll
    for (int ks = 0; ks < 8; ++ks) {
      const int kb = (ks * 32) ^ swz;   // h*16 folded below
#pragma unroll
      for (int mt = 0; mt < 2; ++mt) {
        s8v kf = *(const s8v*)(phb + (mt * 32 + l31) * 256 + (((ks * 32) + h * 16) ^ swz));
        sA[mt] = __builtin_amdgcn_mfma_f32_32x32x16_bf16(kf, qf[ks], sA[mt], 0, 0, 0);
      }
      (void)kb;
    }
    __builtin_amdgcn_s_setprio(0);

    // row max: 31 in-register fmax + 1 shfl (lane l and l^32 share q)
    float mx = sA[0][0];
#pragma unroll
    for (int r = 1; r < 16; ++r) mx = fmaxf(mx, sA[0][r]);
#pragma unroll
    for (int r = 0; r < 16; ++r) mx = fmaxf(mx, sA[1][r]);
    mx = fmaxf(mx, __shfl_xor(mx, 32, 64));

    // defer-max (T13): raw-score threshold 60 -> p <= e^5.3, bf16-safe
    if (__any(mx > m_run + 60.0f)) {
      float mn = fmaxf(m_run, mx);
      float corr = __builtin_amdgcn_exp2f((m_run - mn) * C1);
      m_run = mn;
      l_run *= corr;
#pragma unroll
      for (int r = 0; r < 16; ++r) {
        acc0[r] *= corr; acc1[r] *= corr; acc2[r] *= corr; acc3[r] *= corr;
      }
    }

    // P = exp2(s*C1 - m*C1); pack bf16 pairs; permlane32_swap assembles PV B-frags
    const float nm = -m_run * C1;
    float sum = 0.f;
    s8v bfrag[4];
#pragma unroll
    for (int mt = 0; mt < 2; ++mt) {
#pragma unroll
      for (int k1 = 0; k1 < 2; ++k1) {
        const int base = k1 * 8;
        float p0 = __builtin_amdgcn_exp2f(__builtin_fmaf(sA[mt][base + 0], C1, nm));
        float p1 = __builtin_amdgcn_exp2f(__builtin_fmaf(sA[mt][base + 1], C1, nm));
        float p2 = __builtin_amdgcn_exp2f(__builtin_fmaf(sA[mt][base + 2], C1, nm));
        float p3 = __builtin_amdgcn_exp2f(__builtin_fmaf(sA[mt][base + 3], C1, nm));
        float p4 = __builtin_amdgcn_exp2f(__builtin_fmaf(sA[mt][base + 4], C1, nm));
        float p5 = __builtin_amdgcn_exp2f(__builtin_fmaf(sA[mt][base + 5], C1, nm));
        float p6 = __builtin_amdgcn_exp2f(__builtin_fmaf(sA[mt][base + 6], C1, nm));
        float p7 = __builtin_amdgcn_exp2f(__builtin_fmaf(sA[mt][base + 7], C1, nm));
        sum += ((p0 + p1) + (p2 + p3)) + ((p4 + p5) + (p6 + p7));
        unsigned E0 = f2b2(p0, p1), E1 = f2b2(p2, p3);
        unsigned O0 = f2b2(p4, p5), O1 = f2b2(p6, p7);
        // (E,O) -> lanes<32: [E_own, E_partner]; lanes>=32: [O_partner, O_own]
        asm("v_permlane32_swap_b32 %0, %1" : "+v"(E0), "+v"(O0));
        asm("v_permlane32_swap_b32 %0, %1" : "+v"(E1), "+v"(O1));
        uint4 u = {E0, E1, O0, O1};
        bfrag[mt * 2 + k1] = __builtin_bit_cast(s8v, u);
      }
    }
    sum += __shfl_xor(sum, 32, 64);
    l_run += sum;

    // PV: Y^T[dd][q] += V^T[dd][m] . P^T[m][q]
    __builtin_amdgcn_s_setprio(1);
#pragma unroll
    for (int ks2 = 0; ks2 < 4; ++ks2) {
      const int kb = ((ks2 * 32) + h * 16) ^ swz;
      s8v v0 = *(const s8v*)(gb + (l31) * 128 + kb);
      s8v v1 = *(const s8v*)(gb + (32 + l31) * 128 + kb);
      s8v v2 = *(const s8v*)(gb + (64 + l31) * 128 + kb);
      s8v v3 = *(const s8v*)(gb + (96 + l31) * 128 + kb);
      acc0 = __builtin_amdgcn_mfma_f32_32x32x16_bf16(v0, bfrag[ks2], acc0, 0, 0, 0);
      acc1 = __builtin_amdgcn_mfma_f32_32x32x16_bf16(v1, bfrag[ks2], acc1, 0, 0, 0);
      acc2 = __builtin_amdgcn_mfma_f32_32x32x16_bf16(v2, bfrag[ks2], acc2, 0, 0, 0);
      acc3 = __builtin_amdgcn_mfma_f32_32x32x16_bf16(v3, bfrag[ks2], acc3, 0, 0, 0);
    }
    __builtin_amdgcn_s_setprio(0);

    __syncthreads();
  }

  // write partials: q = qb*128 + w*32 + l31; dd = dt*32 + gi*8 + 4h + (0..3)
  const long gq = (long)bh * 4096 + qb * 128 + w * 32 + l31;
  if (h == 0) pml[gq * 2 + half] = make_float2(m_run, l_run);
  us* py = pY + (gq * 2 + half) * 128;
#pragma unroll
  for (int gi = 0; gi < 4; ++gi) {
    int r0 = gi * 4;
    {
      uint2 u = {f2b2(acc0[r0], acc0[r0 + 1]), f2b2(acc0[r0 + 2], acc0[r0 + 3])};
      *(uint2*)(py + gi * 8 + 4 * h) = u;
    }
    {
      uint2 u = {f2b2(acc1[r0], acc1[r0 + 1]), f2b2(acc1[r0 + 2], acc1[r0 + 3])};
      *(uint2*)(py + 32 + gi * 8 + 4 * h) = u;
    }
    {
      uint2 u = {f2b2(acc2[r0], acc2[r0 + 1]), f2b2(acc2[r0 + 2], acc2[r0 + 3])};
      *(uint2*)(py + 64 + gi * 8 + 4 * h) = u;
    }
    {
      uint2 u = {f2b2(acc3[r0], acc3[r0 + 1]), f2b2(acc3[r0 + 2], acc3[r0 + 3])};
      *(uint2*)(py + 96 + gi * 8 + 4 * h) = u;
    }
  }
}

// ---------------- merge the two KV-half partials -> yt ----------------
__global__ __launch_bounds__(256) void mergek(const us* __restrict__ pY,
                                              const float2* __restrict__ pml,
                                              us* __restrict__ yt) {
  const float C1 = 0.12751802f;
  int idx = blockIdx.x * 256 + threadIdx.x;        // 524288 total
  int gq = idx >> 4, dd8 = (idx & 15) * 8;
  float2 A = pml[gq * 2 + 0], B = pml[gq * 2 + 1];
  float M = fmaxf(A.x, B.x);
  float e0 = __builtin_amdgcn_exp2f((A.x - M) * C1);
  float e1 = __builtin_amdgcn_exp2f((B.x - M) * C1);
  float inv = 1.0f / (A.y * e0 + B.y * e1);
  e0 *= inv; e1 *= inv;
  s8v Y0 = *(const s8v*)(pY + ((long)gq * 2 + 0) * 128 + dd8);
  s8v Y1 = *(const s8v*)(pY + ((long)gq * 2 + 1) * 128 + dd8);
  s8v o;
#pragma unroll
  for (int i = 0; i < 8; ++i) o[i] = f2b(e0 * b2f(Y0[i]) + e1 * b2f(Y1[i]));
  int bh = gq >> 12, q = gq & 4095, b = bh >> 1, head = bh & 1;
  *(s8v*)(yt + ((long)b * 4096 + q) * 256 + head * 128 + dd8) = o;
}

extern "C" void kernel_launch(void* const* d_in, const int* in_sizes, int n_in,
                              void* d_out, int out_size, void* d_ws, size_t ws_size,
                              hipStream_t stream) {
  (void)in_sizes; (void)n_in; (void)out_size;
  const float* x       = (const float*)d_in[0];
  const float* oa      = (const float*)d_in[1];
  const float* mlp_w   = (const float*)d_in[2];
  const float* mlp_b   = (const float*)d_in[3];
  const float* g_w     = (const float*)d_in[4];
  const float* g_b     = (const float*)d_in[5];
  const float* theta_w = (const float*)d_in[6];
  const float* theta_b = (const float*)d_in[7];
  const float* phi_w   = (const float*)d_in[8];
  const float* phi_b   = (const float*)d_in[9];
  const float* out_w   = (const float*)d_in[10];
  const float* out_b   = (const float*)d_in[11];
  float* out = (float*)d_out;
  char* ws = (char*)d_ws;

  us* xf_t   = (us*)(ws + 0L);          // [4096][2048] bf16 (dead once convs done)
  us* pY     = (us*)(ws + 0L);          // [8*4096][2][128] bf16 partials (aliases xf_t)
  us* oat    = (us*)(ws + 16777216L);   // [4096][2048] bf16 (dead after theta conv)
  float2* pml = (float2*)(ws + 16777216L);  // [8*4096][2] float2 (aliases oat)
  us* xt     = (us*)(ws + 33554432L);   // [4096][2048] bf16 (x^T, MLP epilogue)
  us* g_ws   = (us*)(ws + 33554432L);   // [4][256][4096] (aliases xt)
  us* th_ws  = (us*)(ws + 41943040L);   // [8][4096][128]
  us* xc     = (us*)(ws + 50331648L);   // [2048][4096] (x cast, MLP B)
  us* ph_ws  = (us*)(ws + 50331648L);   // [8][4096][128] (aliases xc)
  us* yt     = (us*)(ws + 58720256L);   // [4][4096][256]
  us* g_wb   = (us*)(ws + 67108864L);
  us* th_wb  = (us*)(ws + 67371008L);
  us* ph_wb  = (us*)(ws + 67633152L);
  us* out_wb = (us*)(ws + 67895296L);
  us* mlp_wb = (us*)(ws + 68157440L);   // [4096][4096] bf16 (needs big ws)
  const bool big = ws_size >= 101711872ULL;

  wcast4<<<dim3(32, 4), dim3(256), 0, stream>>>(g_w, g_wb, theta_w, th_wb,
                                                phi_w, ph_wb, out_w, out_wb);
  castk<<<dim3(1024), dim3(256), 0, stream>>>(x, xc, 2097152);
  tcast<<<dim3(64, 32), dim3(256), 0, stream>>>(x, xt, 2048, 4096);
  tcast<<<dim3(64, 32), dim3(256), 0, stream>>>(oa, oat, 2048, 4096);

  // MLP remix: xf_t[m][r] = sum_n mlp_w[m][n]*x[r][n] + x[r][m] + mlp_b[m]
  if (big) {
    castk<<<dim3(1024), dim3(256), 0, stream>>>(mlp_w, mlp_wb, 4194304);
    gemm_nt<0, 0, 0, 1><<<dim3(32, 16, 1), dim3(256), 0, stream>>>(
        mlp_wb, xc, 4096, 4096, 4096, 0, 0, mlp_b, xt, nullptr, xf_t, nullptr);
  } else {
    gemm_nt<0, 1, 0, 1><<<dim3(32, 16, 1), dim3(256), 0, stream>>>(
        mlp_w, xc, 4096, 4096, 4096, 0, 0, mlp_b, xt, nullptr, xf_t, nullptr);
  }

  // theta / phi / g 1x1 convs
  gemm_nt<1, 0, 0, 0><<<dim3(32, 2, 4), dim3(256), 0, stream>>>(
      oat, th_wb, 2048, 512, 512, 512, 0, theta_b, nullptr, nullptr, th_ws, nullptr);
  gemm_nt<1, 0, 0, 0><<<dim3(32, 2, 4), dim3(256), 0, stream>>>(
      xf_t, ph_wb, 2048, 512, 512, 512, 0, phi_b, nullptr, nullptr, ph_ws, nullptr);
  gemm_nt<2, 0, 0, 0><<<dim3(2, 32, 4), dim3(256), 0, stream>>>(
      g_wb, xf_t, 512, 2048, 512, 0, 512, g_b, nullptr, nullptr, g_ws, nullptr);

  // fused softmax attention (kv-split=2) + merge
  attn_k<<<dim3(32, 16), dim3(256), 0, stream>>>(th_ws, ph_ws, g_ws, pY, pml);
  mergek<<<dim3(2048), dim3(256), 0, stream>>>(pY, pml, yt);

  // final conv + residual
  gemm_nt<3, 0, 0, 0><<<dim3(4, 32, 4), dim3(256), 0, stream>>>(
      out_wb, yt, 256, 256, 256, 0, 1048576L, out_b, nullptr, oa, nullptr, out);
}

// Round 6
// 270.555 us; speedup vs baseline: 2.0315x; 1.0360x over previous
//
#include <hip/hip_runtime.h>

typedef unsigned short us;
typedef us s8v __attribute__((ext_vector_type(8)));   // 8 bf16 (4 VGPRs)
typedef us s4v __attribute__((ext_vector_type(4)));
typedef float f4v __attribute__((ext_vector_type(4)));
typedef float f16v __attribute__((ext_vector_type(16)));
typedef __bf16 b2v __attribute__((ext_vector_type(2)));

// HW bf16 convert (RNE via v_cvt_pk_bf16_f32; compiler packs adjacent pairs)
static __device__ __forceinline__ us f2b(float f) {
  return __builtin_bit_cast(us, (__bf16)f);
}
static __device__ __forceinline__ unsigned f2b2(float lo, float hi) {
  b2v v = {(__bf16)lo, (__bf16)hi};
  return __builtin_bit_cast(unsigned, v);
}
static __device__ __forceinline__ float b2f(us s) {
  unsigned u = ((unsigned)s) << 16;
  return __builtin_bit_cast(float, u);
}

#define GLDS(src, dst)                                                        \
  __builtin_amdgcn_global_load_lds(                                           \
      (const __attribute__((address_space(1))) unsigned int*)(src),           \
      (__attribute__((address_space(3))) unsigned int*)(dst), 16, 0, 0)

// ---------------- flat f32 -> bf16 cast ----------------
__global__ __launch_bounds__(256) void castk(const float* __restrict__ in,
                                             us* __restrict__ out, int n4) {
  int i = blockIdx.x * 256 + threadIdx.x;
  int stride = gridDim.x * 256;
  for (; i < n4; i += stride) {
    float4 v = ((const float4*)in)[i];
    s4v s = {f2b(v.x), f2b(v.y), f2b(v.z), f2b(v.w)};
    ((s4v*)out)[i] = s;
  }
}

// 4 weight casts in one launch (each 131072 f32 -> bf16)
__global__ __launch_bounds__(256) void wcast4(const float* __restrict__ s0, us* __restrict__ o0,
                                              const float* __restrict__ s1, us* __restrict__ o1,
                                              const float* __restrict__ s2, us* __restrict__ o2,
                                              const float* __restrict__ s3, us* __restrict__ o3) {
  const float* s; us* o;
  int y = blockIdx.y;
  if (y == 0) { s = s0; o = o0; }
  else if (y == 1) { s = s1; o = o1; }
  else if (y == 2) { s = s2; o = o2; }
  else { s = s3; o = o3; }
  int i = blockIdx.x * 256 + threadIdx.x;
  for (; i < 32768; i += 8192) {
    float4 v = ((const float4*)s)[i];
    s4v r = {f2b(v.x), f2b(v.y), f2b(v.z), f2b(v.w)};
    ((s4v*)o)[i] = r;
  }
}

// ------- transpose-cast: f32 [R][C] -> bf16 [C][R]; optional straight cast out2 --
__global__ __launch_bounds__(256) void tcast(const float* __restrict__ in,
                                             us* __restrict__ out, int R, int C,
                                             us* __restrict__ out2) {
  __shared__ float t[64][65];
  const int tid = threadIdx.x;
  const long r0 = (long)blockIdx.y * 64, c0 = (long)blockIdx.x * 64;
#pragma unroll
  for (int j = 0; j < 4; ++j) {
    int idx = j * 256 + tid;
    int row = idx >> 4, c4 = (idx & 15) * 4;
    float4 v = *(const float4*)(in + (r0 + row) * C + c0 + c4);
    t[row][c4] = v.x; t[row][c4 + 1] = v.y; t[row][c4 + 2] = v.z; t[row][c4 + 3] = v.w;
    if (out2) {
      s4v s = {f2b(v.x), f2b(v.y), f2b(v.z), f2b(v.w)};
      *(s4v*)(out2 + (r0 + row) * C + c0 + c4) = s;
    }
  }
  __syncthreads();
#pragma unroll
  for (int j = 0; j < 4; ++j) {
    int idx = j * 256 + tid;
    int orow = idx >> 4, r4 = (idx & 15) * 4;
    s4v s = {f2b(t[r4][orow]), f2b(t[r4 + 1][orow]), f2b(t[r4 + 2][orow]), f2b(t[r4 + 3][orow])};
    *(s4v*)(out + (c0 + orow) * R + r0 + r4) = s;
  }
}

// byte-offset into a [rows][128 B] LDS tile, XOR-swizzled (T2)
#define SW(row, kb) ((row) * 128 + ((kb) ^ (((row) & 7) << 4)))

// ---------------- generic NT bf16 MFMA GEMM, 128x128 tile, BK=64 ----------------
// bf16 operands stage via global_load_lds (linear LDS dest + pre-swizzled global
// source); f32 operands (AF32/BF32) fall back to reg-staging with swizzled ds_write.
template <int EPI, int AF32, int BF32, int SWZ>
__global__ __launch_bounds__(256) void gemm_nt(
    const void* __restrict__ Av, const void* __restrict__ Bv,
    int lda, int ldb, int K, long aZ, long bZ,
    const float* __restrict__ bias,
    const us* __restrict__ addb16,
    const float* __restrict__ addf32,
    us* __restrict__ outb16,
    float* __restrict__ outf32) {
  __shared__ __align__(16) us lA[128 * 64];
  __shared__ __align__(16) us lB[128 * 64];
  const int tid = threadIdx.x, l = tid & 63;
  const int lr = l & 15, lg = l >> 4;
  const int w = tid >> 6, wr = w >> 1, wc = w & 1;
  int bm, bn;
  if constexpr (SWZ) {   // XCD-contiguous remap (requires nwg % 8 == 0)
    int flat = blockIdx.y * gridDim.x + blockIdx.x;
    int re = (flat & 7) * ((gridDim.x * gridDim.y) >> 3) + (flat >> 3);
    bm = re % gridDim.x; bn = re / gridDim.x;
  } else { bm = blockIdx.x; bn = blockIdx.y; }
  const int z = blockIdx.z;
  const f4v zero = {0.f, 0.f, 0.f, 0.f};
  f4v acc[4][4];
#pragma unroll
  for (int i = 0; i < 4; ++i)
#pragma unroll
    for (int j = 0; j < 4; ++j) acc[i][j] = zero;
  char* lab = (char*)lA;
  char* lbb = (char*)lB;

  // per-lane staging geometry: linear byte -> (row, kb), source kb pre-swizzled
  int rS[4], cS[4];
#pragma unroll
  for (int j = 0; j < 4; ++j) {
    int byte = j * 4096 + tid * 16;
    rS[j] = byte >> 7;
    cS[j] = (byte & 127) ^ ((rS[j] & 7) << 4);
  }
  const char* Ab = (const char*)Av + ((long)z * aZ + (long)bm * 128 * lda) * 2;
  const char* Bb = (const char*)Bv + ((long)z * bZ + (long)bn * 128 * ldb) * 2;

  auto stage = [&](int k0) {
#pragma unroll
    for (int j = 0; j < 4; ++j) {
      if constexpr (AF32) {
        int byte = j * 4096 + tid * 16;
        int row = byte >> 7, kb = byte & 127;
        const float* af = (const float*)Av + (long)z * aZ + (long)(bm * 128 + row) * lda + k0 + (kb >> 1);
        float4 v0 = *(const float4*)af, v1 = *(const float4*)(af + 4);
        s8v va = {f2b(v0.x), f2b(v0.y), f2b(v0.z), f2b(v0.w), f2b(v1.x), f2b(v1.y), f2b(v1.z), f2b(v1.w)};
        *(s8v*)(lab + SW(row, kb)) = va;
      } else {
        GLDS(Ab + (long)rS[j] * lda * 2 + k0 * 2 + cS[j], lab + j * 4096 + w * 1024);
      }
      if constexpr (BF32) {
        int byte = j * 4096 + tid * 16;
        int row = byte >> 7, kb = byte & 127;
        const float* bf_ = (const float*)Bv + (long)z * bZ + (long)(bn * 128 + row) * ldb + k0 + (kb >> 1);
        float4 v0 = *(const float4*)bf_, v1 = *(const float4*)(bf_ + 4);
        s8v vb = {f2b(v0.x), f2b(v0.y), f2b(v0.z), f2b(v0.w), f2b(v1.x), f2b(v1.y), f2b(v1.z), f2b(v1.w)};
        *(s8v*)(lbb + SW(row, kb)) = vb;
      } else {
        GLDS(Bb + (long)rS[j] * ldb * 2 + k0 * 2 + cS[j], lbb + j * 4096 + w * 1024);
      }
    }
  };

  stage(0);
  for (int k0 = 0; k0 < K; k0 += 64) {
    __syncthreads();   // drains staging (vmcnt/lgkm) -> tile ready
#pragma unroll
    for (int ks = 0; ks < 2; ++ks) {
      s8v af[4], bf[4];
      const int kb = ks * 64 + lg * 16;
#pragma unroll
      for (int mi = 0; mi < 4; ++mi) {
        int row = wr * 64 + mi * 16 + lr;
        af[mi] = *(const s8v*)(lab + SW(row, kb));
      }
#pragma unroll
      for (int ni = 0; ni < 4; ++ni) {
        int row = wc * 64 + ni * 16 + lr;
        bf[ni] = *(const s8v*)(lbb + SW(row, kb));
      }
#pragma unroll
      for (int mi = 0; mi < 4; ++mi)
#pragma unroll
        for (int ni = 0; ni < 4; ++ni)
          acc[mi][ni] = __builtin_amdgcn_mfma_f32_16x16x32_bf16(af[mi], bf[ni], acc[mi][ni], 0, 0, 0);
    }
    if (k0 + 64 < K) {
      __syncthreads();   // all waves done reading
      stage(k0 + 64);
    }
  }

#pragma unroll
  for (int mi = 0; mi < 4; ++mi) {
#pragma unroll
    for (int ni = 0; ni < 4; ++ni) {
#pragma unroll
      for (int r = 0; r < 4; ++r) {
        int row = bm * 128 + wr * 64 + mi * 16 + lg * 4 + r;
        int col = bn * 128 + wc * 64 + ni * 16 + lr;
        float v = acc[mi][ni][r];
        if constexpr (EPI == 0) {
          long idx = (long)row * 2048 + col;
          outb16[idx] = f2b(v + b2f(addb16[idx]) + bias[row]);
        } else if constexpr (EPI == 1) {
          long idx = ((long)(z * 2 + (col >> 7)) * 4096 + row) * 128 + (col & 127);
          outb16[idx] = f2b(v + bias[col]);
        } else if constexpr (EPI == 2) {
          long idx = ((long)(z * 256 + row)) * 4096 + col;
          outb16[idx] = f2b(v + bias[row]);
        } else {
          long idx = ((long)(z * 512 + row)) * 4096 + col;
          outf32[idx] = v + bias[row] + addf32[idx];
        }
      }
    }
  }
}

// ---------------- fused flash attention, 32x32 fragments, P in registers --------
// Each wave owns 32 q-rows; block = 4 waves (128 q); KV split in 2 halves across
// blocks (flash-decoding), partials merged by mergek.
// th  [8][4096][128] (Q)   pht [8][4096][128] (K)   g [4][256][4096] (V [dd][m])
// pY  [8*4096][2][128] bf16 unnormalized partial Y;  pml [8*4096][2] float2 (m,l)
__global__ __launch_bounds__(256, 2) void attn_k(const us* __restrict__ th,
                                                 const us* __restrict__ pht,
                                                 const us* __restrict__ g,
                                                 us* __restrict__ pY,
                                                 float2* __restrict__ pml) {
  __shared__ __align__(16) us ph2[2][64 * 128];   // K tiles [m 64][dd 128] (256B rows)
  __shared__ __align__(16) us g2[2][128 * 64];    // V tiles [dd 128][m 64] (128B rows)
  const int tid = threadIdx.x, l = tid & 63, w = tid >> 6;
  const int l31 = l & 31, h = l >> 5;
  const int swz = (l & 7) << 4;
  const int flat = blockIdx.y * 32 + blockIdx.x;
  const int bh = flat & 7, rest = flat >> 3;
  const int half = rest & 1, qb = rest >> 1;
  const int b = bh >> 1, head = bh & 1;
  const int m00 = half * 2048;
  const float C1 = 0.12751802f;                   // (1/sqrt(128)) * log2(e)
  const f16v zero16 = {0.f};

  const char* phsrc = (const char*)(pht + (long)bh * 4096 * 128);
  const char* gsrc = (const char*)(g + (long)(b * 256 + head * 128) * 4096);

  // pre-swizzled per-lane source offsets (linear LDS dest + inv-swz src)
  int koff[4], voff[4];
#pragma unroll
  for (int j = 0; j < 4; ++j) {
    int d = j * 4096 + tid * 16;
    koff[j] = d ^ (((d >> 8) & 7) << 4);
    int rowg = d >> 7, kbg = d & 127;
    voff[j] = rowg * 8192 + (kbg ^ ((rowg & 7) << 4));
  }

  // Q fragments: lane holds q = qb*128 + w*32 + l31, dd = ks*16 + h*8 .. +7
  s8v qf[8];
  {
    const us* thp = th + ((long)bh * 4096 + qb * 128 + w * 32 + l31) * 128 + h * 8;
#pragma unroll
    for (int ks = 0; ks < 8; ++ks) qf[ks] = *(const s8v*)(thp + ks * 16);
  }

  f16v acc0 = zero16, acc1 = zero16, acc2 = zero16, acc3 = zero16;
  float m_run = -1e30f, l_run = 0.f;

  auto stage = [&](int bufi, int m0) {
    char* dk = (char*)ph2[bufi] + w * 1024;
    char* dv = (char*)g2[bufi] + w * 1024;
    const char* sk = phsrc + (long)m0 * 256;
    const char* sv = gsrc + (long)m0 * 2;
#pragma unroll
    for (int j = 0; j < 4; ++j) {
      GLDS(sk + koff[j], dk + j * 4096);
      GLDS(sv + voff[j], dv + j * 4096);
    }
  };

  stage(0, m00);
  __syncthreads();

  for (int t = 0; t < 32; ++t) {
    const int cur = t & 1;
    stage(cur ^ 1, m00 + ((t + 1) & 31) * 64);
    const char* phb = (const char*)ph2[cur];
    const char* gb = (const char*)g2[cur];

    // S^T[m][q] = K . Q^T : lane q = l31; sA[mt] rows m = mt*32 + (r&3)+8*(r>>2)+4h
    f16v sA[2] = {zero16, zero16};
    __builtin_amdgcn_s_setprio(1);
#pragma unroll
    for (int ks = 0; ks < 8; ++ks) {
#pragma unroll
      for (int mt = 0; mt < 2; ++mt) {
        s8v kf = *(const s8v*)(phb + (mt * 32 + l31) * 256 + (((ks * 32) + h * 16) ^ swz));
        sA[mt] = __builtin_amdgcn_mfma_f32_32x32x16_bf16(kf, qf[ks], sA[mt], 0, 0, 0);
      }
    }
    __builtin_amdgcn_s_setprio(0);

    // row max: 31 in-register fmax + 1 shfl (lane l and l^32 share q)
    float mx = sA[0][0];
#pragma unroll
    for (int r = 1; r < 16; ++r) mx = fmaxf(mx, sA[0][r]);
#pragma unroll
    for (int r = 0; r < 16; ++r) mx = fmaxf(mx, sA[1][r]);
    mx = fmaxf(mx, __shfl_xor(mx, 32, 64));

    // defer-max (T13): raw-score threshold 60 -> p <= e^5.3, bf16-safe
    if (__any(mx > m_run + 60.0f)) {
      float mn = fmaxf(m_run, mx);
      float corr = __builtin_amdgcn_exp2f((m_run - mn) * C1);
      m_run = mn;
      l_run *= corr;
#pragma unroll
      for (int r = 0; r < 16; ++r) {
        acc0[r] *= corr; acc1[r] *= corr; acc2[r] *= corr; acc3[r] *= corr;
      }
    }

    // P = exp2(s*C1 - m*C1); pack bf16 pairs; permlane32_swap assembles PV B-frags
    const float nm = -m_run * C1;
    float sum = 0.f;
    s8v bfrag[4];
#pragma unroll
    for (int mt = 0; mt < 2; ++mt) {
#pragma unroll
      for (int k1 = 0; k1 < 2; ++k1) {
        const int base = k1 * 8;
        float p0 = __builtin_amdgcn_exp2f(__builtin_fmaf(sA[mt][base + 0], C1, nm));
        float p1 = __builtin_amdgcn_exp2f(__builtin_fmaf(sA[mt][base + 1], C1, nm));
        float p2 = __builtin_amdgcn_exp2f(__builtin_fmaf(sA[mt][base + 2], C1, nm));
        float p3 = __builtin_amdgcn_exp2f(__builtin_fmaf(sA[mt][base + 3], C1, nm));
        float p4 = __builtin_amdgcn_exp2f(__builtin_fmaf(sA[mt][base + 4], C1, nm));
        float p5 = __builtin_amdgcn_exp2f(__builtin_fmaf(sA[mt][base + 5], C1, nm));
        float p6 = __builtin_amdgcn_exp2f(__builtin_fmaf(sA[mt][base + 6], C1, nm));
        float p7 = __builtin_amdgcn_exp2f(__builtin_fmaf(sA[mt][base + 7], C1, nm));
        sum += ((p0 + p1) + (p2 + p3)) + ((p4 + p5) + (p6 + p7));
        unsigned E0 = f2b2(p0, p1), E1 = f2b2(p2, p3);
        unsigned O0 = f2b2(p4, p5), O1 = f2b2(p6, p7);
        // (E,O) -> lanes<32: [E_own, E_partner]; lanes>=32: [O_partner, O_own]
        asm("v_permlane32_swap_b32 %0, %1" : "+v"(E0), "+v"(O0));
        asm("v_permlane32_swap_b32 %0, %1" : "+v"(E1), "+v"(O1));
        uint4 u = {E0, E1, O0, O1};
        bfrag[mt * 2 + k1] = __builtin_bit_cast(s8v, u);
      }
    }
    sum += __shfl_xor(sum, 32, 64);
    l_run += sum;

    // PV: Y^T[dd][q] += V^T[dd][m] . P^T[m][q]
    __builtin_amdgcn_s_setprio(1);
#pragma unroll
    for (int ks2 = 0; ks2 < 4; ++ks2) {
      const int kb = ((ks2 * 32) + h * 16) ^ swz;
      s8v v0 = *(const s8v*)(gb + (l31) * 128 + kb);
      s8v v1 = *(const s8v*)(gb + (32 + l31) * 128 + kb);
      s8v v2 = *(const s8v*)(gb + (64 + l31) * 128 + kb);
      s8v v3 = *(const s8v*)(gb + (96 + l31) * 128 + kb);
      acc0 = __builtin_amdgcn_mfma_f32_32x32x16_bf16(v0, bfrag[ks2], acc0, 0, 0, 0);
      acc1 = __builtin_amdgcn_mfma_f32_32x32x16_bf16(v1, bfrag[ks2], acc1, 0, 0, 0);
      acc2 = __builtin_amdgcn_mfma_f32_32x32x16_bf16(v2, bfrag[ks2], acc2, 0, 0, 0);
      acc3 = __builtin_amdgcn_mfma_f32_32x32x16_bf16(v3, bfrag[ks2], acc3, 0, 0, 0);
    }
    __builtin_amdgcn_s_setprio(0);

    __syncthreads();
  }

  // write partials: q = qb*128 + w*32 + l31; dd = dt*32 + gi*8 + 4h + (0..3)
  const long gq = (long)bh * 4096 + qb * 128 + w * 32 + l31;
  if (h == 0) pml[gq * 2 + half] = make_float2(m_run, l_run);
  us* py = pY + (gq * 2 + half) * 128;
#pragma unroll
  for (int gi = 0; gi < 4; ++gi) {
    int r0 = gi * 4;
    {
      uint2 u = {f2b2(acc0[r0], acc0[r0 + 1]), f2b2(acc0[r0 + 2], acc0[r0 + 3])};
      *(uint2*)(py + gi * 8 + 4 * h) = u;
    }
    {
      uint2 u = {f2b2(acc1[r0], acc1[r0 + 1]), f2b2(acc1[r0 + 2], acc1[r0 + 3])};
      *(uint2*)(py + 32 + gi * 8 + 4 * h) = u;
    }
    {
      uint2 u = {f2b2(acc2[r0], acc2[r0 + 1]), f2b2(acc2[r0 + 2], acc2[r0 + 3])};
      *(uint2*)(py + 64 + gi * 8 + 4 * h) = u;
    }
    {
      uint2 u = {f2b2(acc3[r0], acc3[r0 + 1]), f2b2(acc3[r0 + 2], acc3[r0 + 3])};
      *(uint2*)(py + 96 + gi * 8 + 4 * h) = u;
    }
  }
}

// ---------------- merge the two KV-half partials -> yt ----------------
__global__ __launch_bounds__(256) void mergek(const us* __restrict__ pY,
                                              const float2* __restrict__ pml,
                                              us* __restrict__ yt) {
  const float C1 = 0.12751802f;
  int idx = blockIdx.x * 256 + threadIdx.x;        // 524288 total
  int gq = idx >> 4, dd8 = (idx & 15) * 8;
  float2 A = pml[gq * 2 + 0], B = pml[gq * 2 + 1];
  float M = fmaxf(A.x, B.x);
  float e0 = __builtin_amdgcn_exp2f((A.x - M) * C1);
  float e1 = __builtin_amdgcn_exp2f((B.x - M) * C1);
  float inv = 1.0f / (A.y * e0 + B.y * e1);
  e0 *= inv; e1 *= inv;
  s8v Y0 = *(const s8v*)(pY + ((long)gq * 2 + 0) * 128 + dd8);
  s8v Y1 = *(const s8v*)(pY + ((long)gq * 2 + 1) * 128 + dd8);
  s8v o;
#pragma unroll
  for (int i = 0; i < 8; ++i) o[i] = f2b(e0 * b2f(Y0[i]) + e1 * b2f(Y1[i]));
  int bh = gq >> 12, q = gq & 4095, b = bh >> 1, head = bh & 1;
  *(s8v*)(yt + ((long)b * 4096 + q) * 256 + head * 128 + dd8) = o;
}

extern "C" void kernel_launch(void* const* d_in, const int* in_sizes, int n_in,
                              void* d_out, int out_size, void* d_ws, size_t ws_size,
                              hipStream_t stream) {
  (void)in_sizes; (void)n_in; (void)out_size;
  const float* x       = (const float*)d_in[0];
  const float* oa      = (const float*)d_in[1];
  const float* mlp_w   = (const float*)d_in[2];
  const float* mlp_b   = (const float*)d_in[3];
  const float* g_w     = (const float*)d_in[4];
  const float* g_b     = (const float*)d_in[5];
  const float* theta_w = (const float*)d_in[6];
  const float* theta_b = (const float*)d_in[7];
  const float* phi_w   = (const float*)d_in[8];
  const float* phi_b   = (const float*)d_in[9];
  const float* out_w   = (const float*)d_in[10];
  const float* out_b   = (const float*)d_in[11];
  float* out = (float*)d_out;
  char* ws = (char*)d_ws;

  us* xf_t   = (us*)(ws + 0L);          // [4096][2048] bf16 (dead once convs done)
  us* pY     = (us*)(ws + 0L);          // [8*4096][2][128] bf16 partials (aliases xf_t)
  us* oat    = (us*)(ws + 16777216L);   // [4096][2048] bf16 (dead after theta conv)
  float2* pml = (float2*)(ws + 16777216L);  // [8*4096][2] float2 (aliases oat)
  us* xt     = (us*)(ws + 33554432L);   // [4096][2048] bf16 (x^T, MLP epilogue)
  us* g_ws   = (us*)(ws + 33554432L);   // [4][256][4096] (aliases xt)
  us* th_ws  = (us*)(ws + 41943040L);   // [8][4096][128]
  us* xc     = (us*)(ws + 50331648L);   // [2048][4096] (x cast, MLP B)
  us* ph_ws  = (us*)(ws + 50331648L);   // [8][4096][128] (aliases xc)
  us* yt     = (us*)(ws + 58720256L);   // [4][4096][256]
  us* g_wb   = (us*)(ws + 67108864L);
  us* th_wb  = (us*)(ws + 67371008L);
  us* ph_wb  = (us*)(ws + 67633152L);
  us* out_wb = (us*)(ws + 67895296L);
  us* mlp_wb = (us*)(ws + 68157440L);   // [4096][4096] bf16 (needs big ws)
  const bool big = ws_size >= 101711872ULL;

  wcast4<<<dim3(32, 4), dim3(256), 0, stream>>>(g_w, g_wb, theta_w, th_wb,
                                                phi_w, ph_wb, out_w, out_wb);
  tcast<<<dim3(64, 32), dim3(256), 0, stream>>>(x, xt, 2048, 4096, xc);
  tcast<<<dim3(64, 32), dim3(256), 0, stream>>>(oa, oat, 2048, 4096, nullptr);

  // MLP remix: xf_t[m][r] = sum_n mlp_w[m][n]*x[r][n] + x[r][m] + mlp_b[m]
  if (big) {
    castk<<<dim3(1024), dim3(256), 0, stream>>>(mlp_w, mlp_wb, 4194304);
    gemm_nt<0, 0, 0, 1><<<dim3(32, 16, 1), dim3(256), 0, stream>>>(
        mlp_wb, xc, 4096, 4096, 4096, 0, 0, mlp_b, xt, nullptr, xf_t, nullptr);
  } else {
    gemm_nt<0, 1, 0, 1><<<dim3(32, 16, 1), dim3(256), 0, stream>>>(
        mlp_w, xc, 4096, 4096, 4096, 0, 0, mlp_b, xt, nullptr, xf_t, nullptr);
  }

  // theta / phi / g 1x1 convs
  gemm_nt<1, 0, 0, 0><<<dim3(32, 2, 4), dim3(256), 0, stream>>>(
      oat, th_wb, 2048, 512, 512, 512, 0, theta_b, nullptr, nullptr, th_ws, nullptr);
  gemm_nt<1, 0, 0, 0><<<dim3(32, 2, 4), dim3(256), 0, stream>>>(
      xf_t, ph_wb, 2048, 512, 512, 512, 0, phi_b, nullptr, nullptr, ph_ws, nullptr);
  gemm_nt<2, 0, 0, 0><<<dim3(2, 32, 4), dim3(256), 0, stream>>>(
      g_wb, xf_t, 512, 2048, 512, 0, 512, g_b, nullptr, nullptr, g_ws, nullptr);

  // fused softmax attention (kv-split=2) + merge
  attn_k<<<dim3(32, 16), dim3(256), 0, stream>>>(th_ws, ph_ws, g_ws, pY, pml);
  mergek<<<dim3(2048), dim3(256), 0, stream>>>(pY, pml, yt);

  // final conv + residual
  gemm_nt<3, 0, 0, 0><<<dim3(4, 32, 4), dim3(256), 0, stream>>>(
      out_wb, yt, 256, 256, 256, 0, 1048576L, out_b, nullptr, oa, nullptr, out);
}

// Round 7
// 255.482 us; speedup vs baseline: 2.1513x; 1.0590x over previous
//
#include <hip/hip_runtime.h>

typedef unsigned short us;
typedef us s8v __attribute__((ext_vector_type(8)));   // 8 bf16 (4 VGPRs)
typedef us s4v __attribute__((ext_vector_type(4)));
typedef float f4v __attribute__((ext_vector_type(4)));
typedef float f16v __attribute__((ext_vector_type(16)));
typedef __bf16 b2v __attribute__((ext_vector_type(2)));

// HW bf16 convert (RNE via v_cvt_pk_bf16_f32; compiler packs adjacent pairs)
static __device__ __forceinline__ us f2b(float f) {
  return __builtin_bit_cast(us, (__bf16)f);
}
static __device__ __forceinline__ unsigned f2b2(float lo, float hi) {
  b2v v = {(__bf16)lo, (__bf16)hi};
  return __builtin_bit_cast(unsigned, v);
}
static __device__ __forceinline__ float b2f(us s) {
  unsigned u = ((unsigned)s) << 16;
  return __builtin_bit_cast(float, u);
}

#define GLDS(src, dst)                                                        \
  __builtin_amdgcn_global_load_lds(                                           \
      (const __attribute__((address_space(1))) unsigned int*)(src),           \
      (__attribute__((address_space(3))) unsigned int*)(dst), 16, 0, 0)

// ---------------- flat f32 -> bf16 cast ----------------
__global__ __launch_bounds__(256) void castk(const float* __restrict__ in,
                                             us* __restrict__ out, int n4) {
  int i = blockIdx.x * 256 + threadIdx.x;
  int stride = gridDim.x * 256;
  for (; i < n4; i += stride) {
    float4 v = ((const float4*)in)[i];
    s4v s = {f2b(v.x), f2b(v.y), f2b(v.z), f2b(v.w)};
    ((s4v*)out)[i] = s;
  }
}

// 4 weight casts in one launch (each 131072 f32 -> bf16)
__global__ __launch_bounds__(256) void wcast4(const float* __restrict__ s0, us* __restrict__ o0,
                                              const float* __restrict__ s1, us* __restrict__ o1,
                                              const float* __restrict__ s2, us* __restrict__ o2,
                                              const float* __restrict__ s3, us* __restrict__ o3) {
  const float* s; us* o;
  int y = blockIdx.y;
  if (y == 0) { s = s0; o = o0; }
  else if (y == 1) { s = s1; o = o1; }
  else if (y == 2) { s = s2; o = o2; }
  else { s = s3; o = o3; }
  int i = blockIdx.x * 256 + threadIdx.x;
  for (; i < 32768; i += 8192) {
    float4 v = ((const float4*)s)[i];
    s4v r = {f2b(v.x), f2b(v.y), f2b(v.z), f2b(v.w)};
    ((s4v*)o)[i] = r;
  }
}

// ------- transpose-cast: f32 [R][C] -> bf16 [C][R]; optional straight cast out2 --
__global__ __launch_bounds__(256) void tcast(const float* __restrict__ in,
                                             us* __restrict__ out, int R, int C,
                                             us* __restrict__ out2) {
  __shared__ float t[64][65];
  const int tid = threadIdx.x;
  const long r0 = (long)blockIdx.y * 64, c0 = (long)blockIdx.x * 64;
#pragma unroll
  for (int j = 0; j < 4; ++j) {
    int idx = j * 256 + tid;
    int row = idx >> 4, c4 = (idx & 15) * 4;
    float4 v = *(const float4*)(in + (r0 + row) * C + c0 + c4);
    t[row][c4] = v.x; t[row][c4 + 1] = v.y; t[row][c4 + 2] = v.z; t[row][c4 + 3] = v.w;
    if (out2) {
      s4v s = {f2b(v.x), f2b(v.y), f2b(v.z), f2b(v.w)};
      *(s4v*)(out2 + (r0 + row) * C + c0 + c4) = s;
    }
  }
  __syncthreads();
#pragma unroll
  for (int j = 0; j < 4; ++j) {
    int idx = j * 256 + tid;
    int orow = idx >> 4, r4 = (idx & 15) * 4;
    s4v s = {f2b(t[r4][orow]), f2b(t[r4 + 1][orow]), f2b(t[r4 + 2][orow]), f2b(t[r4 + 3][orow])};
    *(s4v*)(out + (c0 + orow) * R + r0 + r4) = s;
  }
}

// byte-offset into a [rows][128 B] LDS tile, XOR-swizzled (T2)
#define SW(row, kb) ((row) * 128 + ((kb) ^ (((row) & 7) << 4)))

// ---------------- generic NT bf16 MFMA GEMM, 128x128 tile, BK=64 ----------------
// Double-buffered LDS; next tile's global_load_lds issued BEFORE compute so the
// load latency hides under MFMA; ONE barrier per K-step (drains the in-flight
// loads that ran under the previous compute phase).
template <int EPI, int AF32, int BF32, int SWZ>
__global__ __launch_bounds__(256) void gemm_nt(
    const void* __restrict__ Av, const void* __restrict__ Bv,
    int lda, int ldb, int K, long aZ, long bZ,
    const float* __restrict__ bias,
    const us* __restrict__ addb16,
    const float* __restrict__ addf32,
    us* __restrict__ outb16,
    float* __restrict__ outf32) {
  __shared__ __align__(16) us lA2[2][128 * 64];
  __shared__ __align__(16) us lB2[2][128 * 64];
  const int tid = threadIdx.x, l = tid & 63;
  const int lr = l & 15, lg = l >> 4;
  const int w = tid >> 6, wr = w >> 1, wc = w & 1;
  int bm, bn;
  if constexpr (SWZ) {   // XCD-contiguous remap (requires nwg % 8 == 0)
    int flat = blockIdx.y * gridDim.x + blockIdx.x;
    int re = (flat & 7) * ((gridDim.x * gridDim.y) >> 3) + (flat >> 3);
    bm = re % gridDim.x; bn = re / gridDim.x;
  } else { bm = blockIdx.x; bn = blockIdx.y; }
  const int z = blockIdx.z;
  const f4v zero = {0.f, 0.f, 0.f, 0.f};
  f4v acc[4][4];
#pragma unroll
  for (int i = 0; i < 4; ++i)
#pragma unroll
    for (int j = 0; j < 4; ++j) acc[i][j] = zero;

  // per-lane staging geometry: linear byte -> (row, kb), source kb pre-swizzled
  int rS[4], cS[4];
#pragma unroll
  for (int j = 0; j < 4; ++j) {
    int byte = j * 4096 + tid * 16;
    rS[j] = byte >> 7;
    cS[j] = (byte & 127) ^ ((rS[j] & 7) << 4);
  }
  const char* Ab = (const char*)Av + ((long)z * aZ + (long)bm * 128 * lda) * 2;
  const char* Bb = (const char*)Bv + ((long)z * bZ + (long)bn * 128 * ldb) * 2;

  auto stage = [&](int bufi, int k0) {
    char* lab = (char*)lA2[bufi];
    char* lbb = (char*)lB2[bufi];
#pragma unroll
    for (int j = 0; j < 4; ++j) {
      if constexpr (AF32) {
        int byte = j * 4096 + tid * 16;
        int row = byte >> 7, kb = byte & 127;
        const float* af = (const float*)Av + (long)z * aZ + (long)(bm * 128 + row) * lda + k0 + (kb >> 1);
        float4 v0 = *(const float4*)af, v1 = *(const float4*)(af + 4);
        s8v va = {f2b(v0.x), f2b(v0.y), f2b(v0.z), f2b(v0.w), f2b(v1.x), f2b(v1.y), f2b(v1.z), f2b(v1.w)};
        *(s8v*)(lab + SW(row, kb)) = va;
      } else {
        GLDS(Ab + (long)rS[j] * lda * 2 + k0 * 2 + cS[j], lab + j * 4096 + w * 1024);
      }
      if constexpr (BF32) {
        int byte = j * 4096 + tid * 16;
        int row = byte >> 7, kb = byte & 127;
        const float* bf_ = (const float*)Bv + (long)z * bZ + (long)(bn * 128 + row) * ldb + k0 + (kb >> 1);
        float4 v0 = *(const float4*)bf_, v1 = *(const float4*)(bf_ + 4);
        s8v vb = {f2b(v0.x), f2b(v0.y), f2b(v0.z), f2b(v0.w), f2b(v1.x), f2b(v1.y), f2b(v1.z), f2b(v1.w)};
        *(s8v*)(lbb + SW(row, kb)) = vb;
      } else {
        GLDS(Bb + (long)rS[j] * ldb * 2 + k0 * 2 + cS[j], lbb + j * 4096 + w * 1024);
      }
    }
  };

  stage(0, 0);
  for (int k0 = 0; k0 < K; k0 += 64) {
    const int cur = (k0 >> 6) & 1;
    __syncthreads();                 // buf cur ready; all waves done with buf cur^1
    if (k0 + 64 < K) stage(cur ^ 1, k0 + 64);   // fly under this iter's compute
    const char* lab = (const char*)lA2[cur];
    const char* lbb = (const char*)lB2[cur];
#pragma unroll
    for (int ks = 0; ks < 2; ++ks) {
      s8v af[4], bf[4];
      const int kb = ks * 64 + lg * 16;
#pragma unroll
      for (int mi = 0; mi < 4; ++mi) {
        int row = wr * 64 + mi * 16 + lr;
        af[mi] = *(const s8v*)(lab + SW(row, kb));
      }
#pragma unroll
      for (int ni = 0; ni < 4; ++ni) {
        int row = wc * 64 + ni * 16 + lr;
        bf[ni] = *(const s8v*)(lbb + SW(row, kb));
      }
#pragma unroll
      for (int mi = 0; mi < 4; ++mi)
#pragma unroll
        for (int ni = 0; ni < 4; ++ni)
          acc[mi][ni] = __builtin_amdgcn_mfma_f32_16x16x32_bf16(af[mi], bf[ni], acc[mi][ni], 0, 0, 0);
    }
  }

#pragma unroll
  for (int mi = 0; mi < 4; ++mi) {
#pragma unroll
    for (int ni = 0; ni < 4; ++ni) {
#pragma unroll
      for (int r = 0; r < 4; ++r) {
        int row = bm * 128 + wr * 64 + mi * 16 + lg * 4 + r;
        int col = bn * 128 + wc * 64 + ni * 16 + lr;
        float v = acc[mi][ni][r];
        if constexpr (EPI == 0) {
          long idx = (long)row * 2048 + col;
          outb16[idx] = f2b(v + b2f(addb16[idx]) + bias[row]);
        } else if constexpr (EPI == 1) {
          long idx = ((long)(z * 2 + (col >> 7)) * 4096 + row) * 128 + (col & 127);
          outb16[idx] = f2b(v + bias[col]);
        } else if constexpr (EPI == 2) {
          long idx = ((long)(z * 256 + row)) * 4096 + col;
          outb16[idx] = f2b(v + bias[row]);
        } else {
          long idx = ((long)(z * 512 + row)) * 4096 + col;
          outf32[idx] = v + bias[row] + addf32[idx];
        }
      }
    }
  }
}

// ---------------- fused flash attention, 32x32 fragments, P in registers --------
// Each wave owns 32 q-rows; block = 4 waves (128 q); KV split in 2 halves across
// blocks (flash-decoding), partials merged by mergek.
// th  [8][4096][128] (Q)   pht [8][4096][128] (K)   g [4][256][4096] (V [dd][m])
// pY  [8*4096][2][128] bf16 unnormalized partial Y;  pml [8*4096][2] float2 (m,l)
__global__ __launch_bounds__(256, 2) void attn_k(const us* __restrict__ th,
                                                 const us* __restrict__ pht,
                                                 const us* __restrict__ g,
                                                 us* __restrict__ pY,
                                                 float2* __restrict__ pml) {
  __shared__ __align__(16) us ph2[2][64 * 128];   // K tiles [m 64][dd 128] (256B rows)
  __shared__ __align__(16) us g2[2][128 * 64];    // V tiles [dd 128][m 64] (128B rows)
  const int tid = threadIdx.x, l = tid & 63, w = tid >> 6;
  const int l31 = l & 31, h = l >> 5;
  const int swz = (l & 7) << 4;
  const int flat = blockIdx.y * 32 + blockIdx.x;
  const int bh = flat & 7, rest = flat >> 3;
  const int half = rest & 1, qb = rest >> 1;
  const int b = bh >> 1, head = bh & 1;
  const int m00 = half * 2048;
  const float C1 = 0.12751802f;                   // (1/sqrt(128)) * log2(e)
  const f16v zero16 = {0.f};

  const char* phsrc = (const char*)(pht + (long)bh * 4096 * 128);
  const char* gsrc = (const char*)(g + (long)(b * 256 + head * 128) * 4096);

  // pre-swizzled per-lane source offsets (linear LDS dest + inv-swz src)
  int koff[4], voff[4];
#pragma unroll
  for (int j = 0; j < 4; ++j) {
    int d = j * 4096 + tid * 16;
    koff[j] = d ^ (((d >> 8) & 7) << 4);
    int rowg = d >> 7, kbg = d & 127;
    voff[j] = rowg * 8192 + (kbg ^ ((rowg & 7) << 4));
  }

  // Q fragments: lane holds q = qb*128 + w*32 + l31, dd = ks*16 + h*8 .. +7
  s8v qf[8];
  {
    const us* thp = th + ((long)bh * 4096 + qb * 128 + w * 32 + l31) * 128 + h * 8;
#pragma unroll
    for (int ks = 0; ks < 8; ++ks) qf[ks] = *(const s8v*)(thp + ks * 16);
  }

  f16v acc0 = zero16, acc1 = zero16, acc2 = zero16, acc3 = zero16;
  float m_run = -1e30f, l_run = 0.f;

  auto stage = [&](int bufi, int m0) {
    char* dk = (char*)ph2[bufi] + w * 1024;
    char* dv = (char*)g2[bufi] + w * 1024;
    const char* sk = phsrc + (long)m0 * 256;
    const char* sv = gsrc + (long)m0 * 2;
#pragma unroll
    for (int j = 0; j < 4; ++j) {
      GLDS(sk + koff[j], dk + j * 4096);
      GLDS(sv + voff[j], dv + j * 4096);
    }
  };

  stage(0, m00);
  __syncthreads();

  for (int t = 0; t < 32; ++t) {
    const int cur = t & 1;
    stage(cur ^ 1, m00 + ((t + 1) & 31) * 64);
    const char* phb = (const char*)ph2[cur];
    const char* gb = (const char*)g2[cur];

    // S^T[m][q] = K . Q^T : lane q = l31; sA[mt] rows m = mt*32 + (r&3)+8*(r>>2)+4h
    f16v sA[2] = {zero16, zero16};
    __builtin_amdgcn_s_setprio(1);
#pragma unroll
    for (int ks = 0; ks < 8; ++ks) {
#pragma unroll
      for (int mt = 0; mt < 2; ++mt) {
        s8v kf = *(const s8v*)(phb + (mt * 32 + l31) * 256 + (((ks * 32) + h * 16) ^ swz));
        sA[mt] = __builtin_amdgcn_mfma_f32_32x32x16_bf16(kf, qf[ks], sA[mt], 0, 0, 0);
      }
    }
    __builtin_amdgcn_s_setprio(0);

    // row max: 31 in-register fmax + 1 shfl (lane l and l^32 share q)
    float mx = sA[0][0];
#pragma unroll
    for (int r = 1; r < 16; ++r) mx = fmaxf(mx, sA[0][r]);
#pragma unroll
    for (int r = 0; r < 16; ++r) mx = fmaxf(mx, sA[1][r]);
    mx = fmaxf(mx, __shfl_xor(mx, 32, 64));

    // defer-max (T13): raw-score threshold 60 -> p <= e^5.3, bf16-safe
    if (__any(mx > m_run + 60.0f)) {
      float mn = fmaxf(m_run, mx);
      float corr = __builtin_amdgcn_exp2f((m_run - mn) * C1);
      m_run = mn;
      l_run *= corr;
#pragma unroll
      for (int r = 0; r < 16; ++r) {
        acc0[r] *= corr; acc1[r] *= corr; acc2[r] *= corr; acc3[r] *= corr;
      }
    }

    // P = exp2(s*C1 - m*C1); pack bf16 pairs; permlane32_swap assembles PV B-frags
    const float nm = -m_run * C1;
    float sum = 0.f;
    s8v bfrag[4];
#pragma unroll
    for (int mt = 0; mt < 2; ++mt) {
#pragma unroll
      for (int k1 = 0; k1 < 2; ++k1) {
        const int base = k1 * 8;
        float p0 = __builtin_amdgcn_exp2f(__builtin_fmaf(sA[mt][base + 0], C1, nm));
        float p1 = __builtin_amdgcn_exp2f(__builtin_fmaf(sA[mt][base + 1], C1, nm));
        float p2 = __builtin_amdgcn_exp2f(__builtin_fmaf(sA[mt][base + 2], C1, nm));
        float p3 = __builtin_amdgcn_exp2f(__builtin_fmaf(sA[mt][base + 3], C1, nm));
        float p4 = __builtin_amdgcn_exp2f(__builtin_fmaf(sA[mt][base + 4], C1, nm));
        float p5 = __builtin_amdgcn_exp2f(__builtin_fmaf(sA[mt][base + 5], C1, nm));
        float p6 = __builtin_amdgcn_exp2f(__builtin_fmaf(sA[mt][base + 6], C1, nm));
        float p7 = __builtin_amdgcn_exp2f(__builtin_fmaf(sA[mt][base + 7], C1, nm));
        sum += ((p0 + p1) + (p2 + p3)) + ((p4 + p5) + (p6 + p7));
        unsigned E0 = f2b2(p0, p1), E1 = f2b2(p2, p3);
        unsigned O0 = f2b2(p4, p5), O1 = f2b2(p6, p7);
        // (E,O) -> lanes<32: [E_own, E_partner]; lanes>=32: [O_partner, O_own]
        asm("v_permlane32_swap_b32 %0, %1" : "+v"(E0), "+v"(O0));
        asm("v_permlane32_swap_b32 %0, %1" : "+v"(E1), "+v"(O1));
        uint4 u = {E0, E1, O0, O1};
        bfrag[mt * 2 + k1] = __builtin_bit_cast(s8v, u);
      }
    }
    sum += __shfl_xor(sum, 32, 64);
    l_run += sum;

    // PV: Y^T[dd][q] += V^T[dd][m] . P^T[m][q]
    __builtin_amdgcn_s_setprio(1);
#pragma unroll
    for (int ks2 = 0; ks2 < 4; ++ks2) {
      const int kb = ((ks2 * 32) + h * 16) ^ swz;
      s8v v0 = *(const s8v*)(gb + (l31) * 128 + kb);
      s8v v1 = *(const s8v*)(gb + (32 + l31) * 128 + kb);
      s8v v2 = *(const s8v*)(gb + (64 + l31) * 128 + kb);
      s8v v3 = *(const s8v*)(gb + (96 + l31) * 128 + kb);
      acc0 = __builtin_amdgcn_mfma_f32_32x32x16_bf16(v0, bfrag[ks2], acc0, 0, 0, 0);
      acc1 = __builtin_amdgcn_mfma_f32_32x32x16_bf16(v1, bfrag[ks2], acc1, 0, 0, 0);
      acc2 = __builtin_amdgcn_mfma_f32_32x32x16_bf16(v2, bfrag[ks2], acc2, 0, 0, 0);
      acc3 = __builtin_amdgcn_mfma_f32_32x32x16_bf16(v3, bfrag[ks2], acc3, 0, 0, 0);
    }
    __builtin_amdgcn_s_setprio(0);

    __syncthreads();
  }

  // write partials: q = qb*128 + w*32 + l31; dd = dt*32 + gi*8 + 4h + (0..3)
  const long gq = (long)bh * 4096 + qb * 128 + w * 32 + l31;
  if (h == 0) pml[gq * 2 + half] = make_float2(m_run, l_run);
  us* py = pY + (gq * 2 + half) * 128;
#pragma unroll
  for (int gi = 0; gi < 4; ++gi) {
    int r0 = gi * 4;
    {
      uint2 u = {f2b2(acc0[r0], acc0[r0 + 1]), f2b2(acc0[r0 + 2], acc0[r0 + 3])};
      *(uint2*)(py + gi * 8 + 4 * h) = u;
    }
    {
      uint2 u = {f2b2(acc1[r0], acc1[r0 + 1]), f2b2(acc1[r0 + 2], acc1[r0 + 3])};
      *(uint2*)(py + 32 + gi * 8 + 4 * h) = u;
    }
    {
      uint2 u = {f2b2(acc2[r0], acc2[r0 + 1]), f2b2(acc2[r0 + 2], acc2[r0 + 3])};
      *(uint2*)(py + 64 + gi * 8 + 4 * h) = u;
    }
    {
      uint2 u = {f2b2(acc3[r0], acc3[r0 + 1]), f2b2(acc3[r0 + 2], acc3[r0 + 3])};
      *(uint2*)(py + 96 + gi * 8 + 4 * h) = u;
    }
  }
}

// ---------------- merge the two KV-half partials -> yt ----------------
__global__ __launch_bounds__(256) void mergek(const us* __restrict__ pY,
                                              const float2* __restrict__ pml,
                                              us* __restrict__ yt) {
  const float C1 = 0.12751802f;
  int idx = blockIdx.x * 256 + threadIdx.x;        // 524288 total
  int gq = idx >> 4, dd8 = (idx & 15) * 8;
  float2 A = pml[gq * 2 + 0], B = pml[gq * 2 + 1];
  float M = fmaxf(A.x, B.x);
  float e0 = __builtin_amdgcn_exp2f((A.x - M) * C1);
  float e1 = __builtin_amdgcn_exp2f((B.x - M) * C1);
  float inv = 1.0f / (A.y * e0 + B.y * e1);
  e0 *= inv; e1 *= inv;
  s8v Y0 = *(const s8v*)(pY + ((long)gq * 2 + 0) * 128 + dd8);
  s8v Y1 = *(const s8v*)(pY + ((long)gq * 2 + 1) * 128 + dd8);
  s8v o;
#pragma unroll
  for (int i = 0; i < 8; ++i) o[i] = f2b(e0 * b2f(Y0[i]) + e1 * b2f(Y1[i]));
  int bh = gq >> 12, q = gq & 4095, b = bh >> 1, head = bh & 1;
  *(s8v*)(yt + ((long)b * 4096 + q) * 256 + head * 128 + dd8) = o;
}

extern "C" void kernel_launch(void* const* d_in, const int* in_sizes, int n_in,
                              void* d_out, int out_size, void* d_ws, size_t ws_size,
                              hipStream_t stream) {
  (void)in_sizes; (void)n_in; (void)out_size;
  const float* x       = (const float*)d_in[0];
  const float* oa      = (const float*)d_in[1];
  const float* mlp_w   = (const float*)d_in[2];
  const float* mlp_b   = (const float*)d_in[3];
  const float* g_w     = (const float*)d_in[4];
  const float* g_b     = (const float*)d_in[5];
  const float* theta_w = (const float*)d_in[6];
  const float* theta_b = (const float*)d_in[7];
  const float* phi_w   = (const float*)d_in[8];
  const float* phi_b   = (const float*)d_in[9];
  const float* out_w   = (const float*)d_in[10];
  const float* out_b   = (const float*)d_in[11];
  float* out = (float*)d_out;
  char* ws = (char*)d_ws;

  us* xf_t   = (us*)(ws + 0L);          // [4096][2048] bf16 (dead once convs done)
  us* pY     = (us*)(ws + 0L);          // [8*4096][2][128] bf16 partials (aliases xf_t)
  us* oat    = (us*)(ws + 16777216L);   // [4096][2048] bf16 (dead after theta conv)
  float2* pml = (float2*)(ws + 16777216L);  // [8*4096][2] float2 (aliases oat)
  us* xt     = (us*)(ws + 33554432L);   // [4096][2048] bf16 (x^T, MLP epilogue)
  us* g_ws   = (us*)(ws + 33554432L);   // [4][256][4096] (aliases xt)
  us* th_ws  = (us*)(ws + 41943040L);   // [8][4096][128]
  us* xc     = (us*)(ws + 50331648L);   // [2048][4096] (x cast, MLP B)
  us* ph_ws  = (us*)(ws + 50331648L);   // [8][4096][128] (aliases xc)
  us* yt     = (us*)(ws + 58720256L);   // [4][4096][256]
  us* g_wb   = (us*)(ws + 67108864L);
  us* th_wb  = (us*)(ws + 67371008L);
  us* ph_wb  = (us*)(ws + 67633152L);
  us* out_wb = (us*)(ws + 67895296L);
  us* mlp_wb = (us*)(ws + 68157440L);   // [4096][4096] bf16 (needs big ws)
  const bool big = ws_size >= 101711872ULL;

  wcast4<<<dim3(32, 4), dim3(256), 0, stream>>>(g_w, g_wb, theta_w, th_wb,
                                                phi_w, ph_wb, out_w, out_wb);
  tcast<<<dim3(64, 32), dim3(256), 0, stream>>>(x, xt, 2048, 4096, xc);
  tcast<<<dim3(64, 32), dim3(256), 0, stream>>>(oa, oat, 2048, 4096, nullptr);

  // MLP remix: xf_t[m][r] = sum_n mlp_w[m][n]*x[r][n] + x[r][m] + mlp_b[m]
  if (big) {
    castk<<<dim3(1024), dim3(256), 0, stream>>>(mlp_w, mlp_wb, 4194304);
    gemm_nt<0, 0, 0, 1><<<dim3(32, 16, 1), dim3(256), 0, stream>>>(
        mlp_wb, xc, 4096, 4096, 4096, 0, 0, mlp_b, xt, nullptr, xf_t, nullptr);
  } else {
    gemm_nt<0, 1, 0, 1><<<dim3(32, 16, 1), dim3(256), 0, stream>>>(
        mlp_w, xc, 4096, 4096, 4096, 0, 0, mlp_b, xt, nullptr, xf_t, nullptr);
  }

  // theta / phi / g 1x1 convs
  gemm_nt<1, 0, 0, 0><<<dim3(32, 2, 4), dim3(256), 0, stream>>>(
      oat, th_wb, 2048, 512, 512, 512, 0, theta_b, nullptr, nullptr, th_ws, nullptr);
  gemm_nt<1, 0, 0, 0><<<dim3(32, 2, 4), dim3(256), 0, stream>>>(
      xf_t, ph_wb, 2048, 512, 512, 512, 0, phi_b, nullptr, nullptr, ph_ws, nullptr);
  gemm_nt<2, 0, 0, 0><<<dim3(2, 32, 4), dim3(256), 0, stream>>>(
      g_wb, xf_t, 512, 2048, 512, 0, 512, g_b, nullptr, nullptr, g_ws, nullptr);

  // fused softmax attention (kv-split=2) + merge
  attn_k<<<dim3(32, 16), dim3(256), 0, stream>>>(th_ws, ph_ws, g_ws, pY, pml);
  mergek<<<dim3(2048), dim3(256), 0, stream>>>(pY, pml, yt);

  // final conv + residual
  gemm_nt<3, 0, 0, 0><<<dim3(4, 32, 4), dim3(256), 0, stream>>>(
      out_wb, yt, 256, 256, 256, 0, 1048576L, out_b, nullptr, oa, nullptr, out);
}